// Round 1
// baseline (2833.169 us; speedup 1.0000x reference)
//
#include <hip/hip_runtime.h>
#include <hip/hip_bf16.h>

// Sizes (fixed by the problem)
#define B_ 32
#define T_ 64
#define L_ 1500
#define H_ 128
#define DC_ 100
#define L1OUT 499   // (1500-5)/3+1
#define L2OUT 165   // (499-5)/3+1
#define L3OUT 54    // (165-5)/3+1
#define FLAT_ 1728  // 32*54

__device__ __forceinline__ float leakyf(float v) { return v > 0.f ? v : 0.01f * v; }
__device__ __forceinline__ float sigmoidf_(float v) { return 1.f / (1.f + expf(-v)); }

// ---------------------------------------------------------------------------
// Kernel 1: fused conv1 + conv2.
// Grid: (3 l2-tiles, 2048 n). Block: 256 threads = 16 (c2) x 16 (l2).
// Per block: l2 tile of 64 (tiles at l2_0 = 0,64,101; overlap region written
// twice with identical values - benign). conv1 tile (c1-chunked by 32) staged
// in LDS, conv2 register-tiled 2 c2 x 4 l2 per thread.
// ---------------------------------------------------------------------------
__global__ __launch_bounds__(256) void k_conv12(
    const float* __restrict__ X, const float* __restrict__ w1,
    const float* __restrict__ w2, float* __restrict__ c2out) {
  __shared__ __align__(16) float Xs[600];        // 584 used + pad
  __shared__ __align__(16) float w1s[640];       // full conv1 weights
  __shared__ __align__(16) float s1[32 * 196];   // conv1 chunk [c1l][196]
  __shared__ __align__(16) float ws2[32 * 160];  // w2 chunk [c1l][c2*5+k]

  const int tile = blockIdx.x;
  const int n = blockIdx.y;
  const int l2_0 = (tile == 0) ? 0 : (tile == 1 ? 64 : 101);
  const int P0 = 3 * l2_0;  // first conv1 position needed
  const int tid = threadIdx.x;

  const float* Xn = X + n * L_ + 3 * P0;
  for (int i = tid; i < 584; i += 256) Xs[i] = Xn[i];
  for (int i = tid; i < 640; i += 256) w1s[i] = w1[i];

  const int c2t = tid & 15;   // 16 threads over c2, 2 each
  const int l2t = tid >> 4;   // 16 threads over l2, 4 each

  float acc[2][4] = {{0.f, 0.f, 0.f, 0.f}, {0.f, 0.f, 0.f, 0.f}};

  for (int cc = 0; cc < 4; ++cc) {  // c1 chunks of 32
    __syncthreads();  // protect previous chunk's readers
    // stage w2 chunk: ws2[c1l*160 + c2*5 + k]
    for (int d = tid; d < 5120; d += 256) {
      int c1l = d / 160;
      int r = d - c1l * 160;
      int c2 = r / 5;
      int k = r - c2 * 5;
      ws2[d] = w2[c2 * 640 + (cc * 32 + c1l) * 5 + k];
    }
    // conv1 chunk: 32 c1l x 49 position-groups of 4
    for (int d = tid; d < 32 * 49; d += 256) {
      int c1l = d / 49;
      int pg = d - c1l * 49;
      const float* wr = w1s + (cc * 32 + c1l) * 5;
      float w0 = wr[0], wv1 = wr[1], wv2 = wr[2], wv3 = wr[3], wv4 = wr[4];
      float4 x0 = *(const float4*)(Xs + 12 * pg);
      float4 x1 = *(const float4*)(Xs + 12 * pg + 4);
      float4 x2 = *(const float4*)(Xs + 12 * pg + 8);
      float4 x3 = *(const float4*)(Xs + 12 * pg + 12);
      float xw[16] = {x0.x, x0.y, x0.z, x0.w, x1.x, x1.y, x1.z, x1.w,
                      x2.x, x2.y, x2.z, x2.w, x3.x, x3.y, x3.z, x3.w};
      float4 o;
      o.x = leakyf(xw[0] * w0 + xw[1] * wv1 + xw[2] * wv2 + xw[3] * wv3 + xw[4] * wv4);
      o.y = leakyf(xw[3] * w0 + xw[4] * wv1 + xw[5] * wv2 + xw[6] * wv3 + xw[7] * wv4);
      o.z = leakyf(xw[6] * w0 + xw[7] * wv1 + xw[8] * wv2 + xw[9] * wv3 + xw[10] * wv4);
      o.w = leakyf(xw[9] * w0 + xw[10] * wv1 + xw[11] * wv2 + xw[12] * wv3 + xw[13] * wv4);
      *(float4*)(s1 + c1l * 196 + 4 * pg) = o;  // pad rows: idx<=195 safe
    }
    __syncthreads();
    // conv2 accumulate over this c1 chunk
    for (int c1l = 0; c1l < 32; ++c1l) {
      float4 a0 = *(const float4*)(s1 + c1l * 196 + 12 * l2t);
      float4 a1 = *(const float4*)(s1 + c1l * 196 + 12 * l2t + 4);
      float4 a2 = *(const float4*)(s1 + c1l * 196 + 12 * l2t + 8);
      float4 a3 = *(const float4*)(s1 + c1l * 196 + 12 * l2t + 12);
      float win[16] = {a0.x, a0.y, a0.z, a0.w, a1.x, a1.y, a1.z, a1.w,
                       a2.x, a2.y, a2.z, a2.w, a3.x, a3.y, a3.z, a3.w};
#pragma unroll
      for (int ccc = 0; ccc < 2; ++ccc) {
        const float* wp = ws2 + c1l * 160 + (c2t * 2 + ccc) * 5;
        float b0 = wp[0], b1 = wp[1], b2 = wp[2], b3 = wp[3], b4 = wp[4];
#pragma unroll
        for (int j = 0; j < 4; ++j) {
          acc[ccc][j] += win[3 * j] * b0 + win[3 * j + 1] * b1 +
                         win[3 * j + 2] * b2 + win[3 * j + 3] * b3 +
                         win[3 * j + 4] * b4;
        }
      }
    }
  }
  // write (all l2 in all tiles are < 165 by construction)
#pragma unroll
  for (int ccc = 0; ccc < 2; ++ccc) {
    int c2 = c2t * 2 + ccc;
#pragma unroll
    for (int j = 0; j < 4; ++j) {
      int l2 = l2_0 + l2t * 4 + j;
      c2out[(n * 32 + c2) * L2OUT + l2] = leakyf(acc[ccc][j]);
    }
  }
}

// ---------------------------------------------------------------------------
// Kernel 2: fused conv3 + linear + layer0 input gates (xg0 = feats @ w_ih0^T).
// Grid: 1024 blocks x 256 threads, 2 n per block.
// ---------------------------------------------------------------------------
__global__ __launch_bounds__(256) void k_conv3lin(
    const float* __restrict__ c2o, const float* __restrict__ w3,
    const float* __restrict__ linw, const float* __restrict__ wih0,
    float* __restrict__ xg0) {
  __shared__ __align__(16) float s2[2 * 32 * 172];  // rows padded 165->172
  __shared__ __align__(16) float w3s[5120];
  __shared__ __align__(16) float s3[2][FLAT_];
  __shared__ float fe[2][DC_];

  const int nb = blockIdx.x;
  const int tid = threadIdx.x;

  for (int i = tid; i < 5120; i += 256) w3s[i] = w3[i];
  for (int nn = 0; nn < 2; ++nn) {
    const float* src = c2o + (size_t)(nb * 2 + nn) * (32 * L2OUT);
    for (int i = tid; i < 32 * L2OUT; i += 256) {
      int c2 = i / L2OUT;
      int l2 = i - c2 * L2OUT;
      s2[(nn * 32 + c2) * 172 + l2] = src[i];
    }
  }
  __syncthreads();

  // conv3: tasks = nn(2) x c3(32) x l3-groups(14 of 4)
  for (int d = tid; d < 2 * 32 * 14; d += 256) {
    int nn = d / 448;
    int r = d - nn * 448;
    int c3 = r / 14;
    int l3g = r - c3 * 14;
    float acc4[4] = {0.f, 0.f, 0.f, 0.f};
    for (int c2 = 0; c2 < 32; ++c2) {
      const float* sp = s2 + (nn * 32 + c2) * 172 + 12 * l3g;
      float4 a0 = *(const float4*)(sp);
      float4 a1 = *(const float4*)(sp + 4);
      float4 a2 = *(const float4*)(sp + 8);
      float4 a3 = *(const float4*)(sp + 12);
      float win[16] = {a0.x, a0.y, a0.z, a0.w, a1.x, a1.y, a1.z, a1.w,
                       a2.x, a2.y, a2.z, a2.w, a3.x, a3.y, a3.z, a3.w};
      const float* wp = w3s + c3 * 160 + c2 * 5;
      float b0 = wp[0], b1 = wp[1], b2 = wp[2], b3 = wp[3], b4 = wp[4];
#pragma unroll
      for (int j = 0; j < 4; ++j) {
        acc4[j] += win[3 * j] * b0 + win[3 * j + 1] * b1 + win[3 * j + 2] * b2 +
                   win[3 * j + 3] * b3 + win[3 * j + 4] * b4;
      }
    }
#pragma unroll
    for (int j = 0; j < 4; ++j) {
      int l3 = l3g * 4 + j;
      if (l3 < L3OUT) s3[nn][c3 * L3OUT + l3] = leakyf(acc4[j]);
    }
  }
  __syncthreads();

  // linear: one wave per (nn, j) dot of length 1728, coalesced weight reads
  const int wv = tid >> 6, lane = tid & 63;
  for (int idx = wv; idx < 200; idx += 4) {
    int nn = idx & 1, j = idx >> 1;
    const float* wr = linw + j * FLAT_;
    float p = 0.f;
    for (int i = lane; i < FLAT_; i += 64) p += wr[i] * s3[nn][i];
#pragma unroll
    for (int off = 32; off > 0; off >>= 1) p += __shfl_down(p, off, 64);
    if (lane == 0) fe[nn][j] = p;
  }
  __syncthreads();

  // xg0[n][j] = dot(fe[n], w_ih0[j])
  for (int nn = 0; nn < 2; ++nn) {
    for (int j = tid; j < 512; j += 256) {
      const float* wr = wih0 + j * DC_;
      float v = 0.f;
      for (int k = 0; k < DC_; ++k) v += fe[nn][k] * wr[k];
      xg0[(size_t)(nb * 2 + nn) * 512 + j] = v;
    }
  }
}

// ---------------------------------------------------------------------------
// Kernel 3: both LSTM layers + final FCs. One block per batch element.
// 512 threads: thread j computes gate j. Mask == early exit at t==len
// (state frozen afterwards => identical result).
// ---------------------------------------------------------------------------
__global__ __launch_bounds__(512) void k_lstm(
    const float* __restrict__ xg0, const float* __restrict__ whh0,
    const float* __restrict__ wih1, const float* __restrict__ whh1,
    const float* __restrict__ fc1, const float* __restrict__ fc2,
    const int* __restrict__ lengths, float* __restrict__ out) {
  __shared__ __align__(16) float h0[H_], c0[H_], h1[H_], c1[H_];
  __shared__ __align__(16) float gs[512];
  __shared__ float tmp10[10];

  const int b = blockIdx.x;
  const int tid = threadIdx.x;
  if (tid < H_) { h0[tid] = 0.f; c0[tid] = 0.f; h1[tid] = 0.f; c1[tid] = 0.f; }
  const int len = lengths[b];
  const float4* w0r = (const float4*)(whh0 + tid * H_);
  const float4* w1ir = (const float4*)(wih1 + tid * H_);
  const float4* w1hr = (const float4*)(whh1 + tid * H_);
  __syncthreads();

  for (int t = 0; t < len; ++t) {
    // layer 0 gates
    float a = xg0[((size_t)b * T_ + t) * 512 + tid];
#pragma unroll 8
    for (int k4 = 0; k4 < 32; ++k4) {
      float4 w = w0r[k4];
      float4 h = *(const float4*)(h0 + 4 * k4);
      a += h.x * w.x + h.y * w.y + h.z * w.z + h.w * w.w;
    }
    gs[tid] = a;
    __syncthreads();
    if (tid < H_) {
      float ig = sigmoidf_(gs[tid]);
      float fg = sigmoidf_(gs[H_ + tid]);
      float gg = tanhf(gs[2 * H_ + tid]);
      float og = sigmoidf_(gs[3 * H_ + tid]);
      float cn = fg * c0[tid] + ig * gg;
      c0[tid] = cn;
      h0[tid] = og * tanhf(cn);
    }
    __syncthreads();
    // layer 1 gates (uses new h0 = hs1[t], old h1)
    float a1 = 0.f;
#pragma unroll 8
    for (int k4 = 0; k4 < 32; ++k4) {
      float4 w = w1ir[k4];
      float4 h = *(const float4*)(h0 + 4 * k4);
      a1 += h.x * w.x + h.y * w.y + h.z * w.z + h.w * w.w;
    }
#pragma unroll 8
    for (int k4 = 0; k4 < 32; ++k4) {
      float4 w = w1hr[k4];
      float4 h = *(const float4*)(h1 + 4 * k4);
      a1 += h.x * w.x + h.y * w.y + h.z * w.z + h.w * w.w;
    }
    gs[tid] = a1;
    __syncthreads();
    if (tid < H_) {
      float ig = sigmoidf_(gs[tid]);
      float fg = sigmoidf_(gs[H_ + tid]);
      float gg = tanhf(gs[2 * H_ + tid]);
      float og = sigmoidf_(gs[3 * H_ + tid]);
      float cn = fg * c1[tid] + ig * gg;
      c1[tid] = cn;
      h1[tid] = og * tanhf(cn);
    }
    __syncthreads();
  }

  if (tid < 10) {
    const float* fr = fc1 + tid * H_;
    float s = 0.f;
    for (int k = 0; k < H_; ++k) s += h1[k] * fr[k];
    tmp10[tid] = leakyf(s);
  }
  __syncthreads();
  if (tid < 2) {
    const float* fr = fc2 + tid * 10;
    float s = 0.f;
    for (int j = 0; j < 10; ++j) s += tmp10[j] * fr[j];
    out[b * 2 + tid] = leakyf(s);
  }
}

extern "C" void kernel_launch(void* const* d_in, const int* in_sizes, int n_in,
                              void* d_out, int out_size, void* d_ws, size_t ws_size,
                              hipStream_t stream) {
  const float* X = (const float*)d_in[0];
  const int* lengths = (const int*)d_in[1];
  const float* w1 = (const float*)d_in[2];
  const float* w2 = (const float*)d_in[3];
  const float* w3 = (const float*)d_in[4];
  const float* linw = (const float*)d_in[5];
  const float* wih0 = (const float*)d_in[6];
  const float* whh0 = (const float*)d_in[7];
  const float* wih1 = (const float*)d_in[8];
  const float* whh1 = (const float*)d_in[9];
  const float* fc1 = (const float*)d_in[10];
  const float* fc2 = (const float*)d_in[11];

  float* conv2o = (float*)d_ws;                       // 2048*32*165 f32 = 43.25 MB
  float* xg0 = (float*)((char*)d_ws + 43253760);      // 2048*512 f32 = 4 MB

  k_conv12<<<dim3(3, 2048), 256, 0, stream>>>(X, w1, w2, conv2o);
  k_conv3lin<<<1024, 256, 0, stream>>>(conv2o, w3, linw, wih0, xg0);
  k_lstm<<<32, 512, 0, stream>>>(xg0, whh0, wih1, whh1, fc1, fc2, lengths,
                                 (float*)d_out);
}

// Round 2
// 1439.677 us; speedup vs baseline: 1.9679x; 1.9679x over previous
//
#include <hip/hip_runtime.h>
#include <hip/hip_bf16.h>

#define B_ 32
#define T_ 64
#define L_ 1500
#define H_ 128
#define DC_ 100
#define L1OUT 499
#define L2OUT 165
#define L3OUT 54
#define FLAT_ 1728

__device__ __forceinline__ float leakyf(float v) { return v > 0.f ? v : 0.01f * v; }
__device__ __forceinline__ float sigmoidf_(float v) { return 1.f / (1.f + expf(-v)); }
__device__ __forceinline__ float wred64(float p) {
#pragma unroll
  for (int off = 32; off > 0; off >>= 1) p += __shfl_down(p, off, 64);
  return p;
}

// ---------------------------------------------------------------------------
// Kernel 1: fused conv1 + conv2. One block per n (2048 blocks, 192 threads).
// conv1 staged in LDS in chunks of 16 c1; conv2 register tile 4 c2 x 8 l2.
// Weights LDS rows padded to 13 floats -> conflict-free scalar reads.
// LDS = 6016 + 32768 + 26624 = 65408 B (<= 64 KiB), 2 blocks/CU.
// ---------------------------------------------------------------------------
__global__ __launch_bounds__(192) void k_conv12(
    const float* __restrict__ X, const float* __restrict__ w1,
    const float* __restrict__ w2, float* __restrict__ c2out) {
  __shared__ __align__(16) float Xs[1504];
  __shared__ __align__(16) float s1[16 * 512];    // conv1 chunk [c1l][512]
  __shared__ float ws2[16 * 32 * 13];             // w2 chunk [c1l][c2][13]

  const int n = blockIdx.x;
  const int tid = threadIdx.x;

  const float* Xn = X + n * L_;
  for (int i = tid; i < L_; i += 192) Xs[i] = Xn[i];

  const int active = (tid < 168);
  const int c2g = tid / 21;   // 0..7 (for tid<168)
  const int l2g = tid % 21;   // 0..20

  float acc[4][8];
#pragma unroll
  for (int a = 0; a < 4; ++a)
#pragma unroll
    for (int b = 0; b < 8; ++b) acc[a][b] = 0.f;

  for (int cc = 0; cc < 8; ++cc) {  // chunks of 16 c1
    __syncthreads();
    // stage w2 chunk: [c1l][c2][13]
    for (int d = tid; d < 2560; d += 192) {
      int c1l = d / 160;
      int r = d - c1l * 160;
      int c2 = r / 5;
      int k = r - c2 * 5;
      ws2[(c1l * 32 + c2) * 13 + k] = w2[c2 * 640 + (cc * 16 + c1l) * 5 + k];
    }
    // conv1 chunk: 16 c1l x 125 position-groups of 4 (positions 0..499;
    // p=499 garbage but only feeds guarded-out outputs)
    for (int d = tid; d < 2000; d += 192) {
      int c1l = d / 125;
      int pg = d - c1l * 125;
      const float* wr = w1 + (cc * 16 + c1l) * 5;
      float w0 = wr[0], wv1 = wr[1], wv2 = wr[2], wv3 = wr[3], wv4 = wr[4];
      float4 x0 = *(const float4*)(Xs + 12 * pg);
      float4 x1 = *(const float4*)(Xs + 12 * pg + 4);
      float4 x2 = *(const float4*)(Xs + 12 * pg + 8);
      float4 x3 = *(const float4*)(Xs + 12 * pg + 12);
      float xw[16] = {x0.x, x0.y, x0.z, x0.w, x1.x, x1.y, x1.z, x1.w,
                      x2.x, x2.y, x2.z, x2.w, x3.x, x3.y, x3.z, x3.w};
      float4 o;
      o.x = leakyf(xw[0] * w0 + xw[1] * wv1 + xw[2] * wv2 + xw[3] * wv3 + xw[4] * wv4);
      o.y = leakyf(xw[3] * w0 + xw[4] * wv1 + xw[5] * wv2 + xw[6] * wv3 + xw[7] * wv4);
      o.z = leakyf(xw[6] * w0 + xw[7] * wv1 + xw[8] * wv2 + xw[9] * wv3 + xw[10] * wv4);
      o.w = leakyf(xw[9] * w0 + xw[10] * wv1 + xw[11] * wv2 + xw[12] * wv3 + xw[13] * wv4);
      *(float4*)(s1 + c1l * 512 + 4 * pg) = o;
    }
    __syncthreads();
    if (active) {
      for (int c1l = 0; c1l < 16; ++c1l) {
        const float* srow = s1 + c1l * 512 + 24 * l2g;
        float xw[28];
#pragma unroll
        for (int q = 0; q < 7; ++q) {
          float4 v = *(const float4*)(srow + 4 * q);
          xw[4 * q] = v.x; xw[4 * q + 1] = v.y; xw[4 * q + 2] = v.z; xw[4 * q + 3] = v.w;
        }
#pragma unroll
        for (int cc2 = 0; cc2 < 4; ++cc2) {
          const float* wp = ws2 + (c1l * 32 + c2g * 4 + cc2) * 13;
          float b0 = wp[0], b1 = wp[1], b2 = wp[2], b3 = wp[3], b4 = wp[4];
#pragma unroll
          for (int j = 0; j < 8; ++j) {
            acc[cc2][j] += xw[3 * j] * b0 + xw[3 * j + 1] * b1 +
                           xw[3 * j + 2] * b2 + xw[3 * j + 3] * b3 +
                           xw[3 * j + 4] * b4;
          }
        }
      }
    }
  }
  if (active) {
#pragma unroll
    for (int cc2 = 0; cc2 < 4; ++cc2) {
      int c2 = c2g * 4 + cc2;
#pragma unroll
      for (int j = 0; j < 8; ++j) {
        int l2 = l2g * 8 + j;
        if (l2 < L2OUT) c2out[(n * 32 + c2) * L2OUT + l2] = leakyf(acc[cc2][j]);
      }
    }
  }
}

// ---------------------------------------------------------------------------
// Kernel 2: fused conv3 + linear + layer0 input gates. 1024 blocks x 512 thr,
// 2 n per block. w3 read from global (L1/L2-cached broadcast).
// LDS = 43072 + 13824 + 800 = 57696 B.
// ---------------------------------------------------------------------------
__global__ __launch_bounds__(512) void k_conv3lin(
    const float* __restrict__ c2o, const float* __restrict__ w3,
    const float* __restrict__ linw, const float* __restrict__ wih0,
    float* __restrict__ xg0) {
  __shared__ __align__(16) float s2[2 * 32 * 168 + 8];
  __shared__ __align__(16) float s3[2][FLAT_];
  __shared__ float fe[2][DC_];

  const int nb = blockIdx.x;
  const int tid = threadIdx.x;

  // stage conv2 output rows (padded 165 -> 168)
  const float* src = c2o + (size_t)nb * 2 * (32 * L2OUT);
  for (int i = tid; i < 2 * 32 * L2OUT; i += 512) {
    int grp = i / L2OUT;        // nn*32 + c2
    int l2 = i - grp * L2OUT;
    s2[grp * 168 + l2] = src[i];
  }
  __syncthreads();

  // conv3: tasks = nn(2) x c3(32) x l3g(14 of Tl=4)
  for (int d = tid; d < 896; d += 512) {
    int nn = d / 448;
    int r = d - nn * 448;
    int c3 = r / 14;
    int l3g = r - c3 * 14;
    float acc4[4] = {0.f, 0.f, 0.f, 0.f};
    for (int c2 = 0; c2 < 32; ++c2) {
      const float* sp = s2 + (nn * 32 + c2) * 168 + 12 * l3g;
      float4 a0 = *(const float4*)(sp);
      float4 a1 = *(const float4*)(sp + 4);
      float4 a2 = *(const float4*)(sp + 8);
      float4 a3 = *(const float4*)(sp + 12);
      float win[16] = {a0.x, a0.y, a0.z, a0.w, a1.x, a1.y, a1.z, a1.w,
                       a2.x, a2.y, a2.z, a2.w, a3.x, a3.y, a3.z, a3.w};
      const float* wp = w3 + c3 * 160 + c2 * 5;
      float b0 = wp[0], b1 = wp[1], b2 = wp[2], b3 = wp[3], b4 = wp[4];
#pragma unroll
      for (int j = 0; j < 4; ++j) {
        acc4[j] += win[3 * j] * b0 + win[3 * j + 1] * b1 + win[3 * j + 2] * b2 +
                   win[3 * j + 3] * b3 + win[3 * j + 4] * b4;
      }
    }
#pragma unroll
    for (int j = 0; j < 4; ++j) {
      int l3 = l3g * 4 + j;
      if (l3 < L3OUT) s3[nn][c3 * L3OUT + l3] = leakyf(acc4[j]);
    }
  }
  __syncthreads();

  const int wv = tid >> 6, lane = tid & 63;
  // linear: wave per (nn, j) dot of 1728
  for (int idx = wv; idx < 200; idx += 8) {
    int nn = idx & 1, j = idx >> 1;
    const float* wr = linw + j * FLAT_;
    float p = 0.f;
    for (int i = lane; i < FLAT_; i += 64) p += wr[i] * s3[nn][i];
    p = wred64(p);
    if (lane == 0) fe[nn][j] = p;
  }
  __syncthreads();

  // xg0: wave per (nn, j) dot of 100
  for (int idx = wv; idx < 1024; idx += 8) {
    int nn = idx & 1, j = idx >> 1;
    const float* wr = wih0 + j * DC_;
    float p = 0.f;
    if (lane < DC_) p = wr[lane] * fe[nn][lane];
    if (lane < DC_ - 64) p += wr[lane + 64] * fe[nn][lane + 64];
    p = wred64(p);
    if (lane == 0) xg0[((size_t)(nb * 2 + nn)) * 512 + j] = p;
  }
}

// ---------------------------------------------------------------------------
// Kernel 3: transpose [512][K=128] -> [128][512]
// ---------------------------------------------------------------------------
__global__ __launch_bounds__(256) void k_tr(const float* __restrict__ src,
                                            float* __restrict__ dst) {
  int o = blockIdx.x * 256 + threadIdx.x;
#pragma unroll
  for (int r = 0; r < 4; ++r) {
    int k = o >> 9;
    int j = o & 511;
    dst[o] = src[j * 128 + k];
    o += 16384;
  }
}

// ---------------------------------------------------------------------------
// Kernel 4: LSTM layer 0. 32 blocks x 512 thr; whh0 row held in 128 VGPRs.
// Writes hs1[b][t][128] for t < len.
// ---------------------------------------------------------------------------
__global__ __launch_bounds__(512) void k_lstm0(
    const float* __restrict__ xg0, const float* __restrict__ whh0T,
    const int* __restrict__ lengths, float* __restrict__ hs1) {
  __shared__ __align__(16) float h0s[H_];
  __shared__ float gs[512];
  const int b = blockIdx.x;
  const int tid = threadIdx.x;
  float w[128];
#pragma unroll
  for (int k = 0; k < 128; ++k) w[k] = whh0T[k * 512 + tid];
  if (tid < H_) h0s[tid] = 0.f;
  float c = 0.f;
  const int len = lengths[b];
  __syncthreads();
  for (int t = 0; t < len; ++t) {
    float a0 = xg0[((size_t)(b * T_ + t)) * 512 + tid];
    float a1 = 0.f;
#pragma unroll
    for (int k4 = 0; k4 < 32; k4 += 2) {
      float4 h = *(const float4*)(h0s + 4 * k4);
      a0 += h.x * w[4 * k4] + h.y * w[4 * k4 + 1] + h.z * w[4 * k4 + 2] + h.w * w[4 * k4 + 3];
      float4 h2 = *(const float4*)(h0s + 4 * k4 + 4);
      a1 += h2.x * w[4 * k4 + 4] + h2.y * w[4 * k4 + 5] + h2.z * w[4 * k4 + 6] + h2.w * w[4 * k4 + 7];
    }
    gs[tid] = a0 + a1;
    __syncthreads();
    if (tid < H_) {
      float ig = sigmoidf_(gs[tid]);
      float fg = sigmoidf_(gs[H_ + tid]);
      float gg = tanhf(gs[2 * H_ + tid]);
      float og = sigmoidf_(gs[3 * H_ + tid]);
      c = fg * c + ig * gg;
      float hn = og * tanhf(c);
      h0s[tid] = hn;
      hs1[((size_t)(b * T_ + t)) * H_ + tid] = hn;
    }
    __syncthreads();
  }
}

// ---------------------------------------------------------------------------
// Kernel 5: xg1 = hs1 @ wih1^T, 256 blocks x 512 thr, 8 rows per block.
// ---------------------------------------------------------------------------
__global__ __launch_bounds__(512) void k_xg1(
    const float* __restrict__ hs1, const float* __restrict__ wih1T,
    float* __restrict__ xg1) {
  __shared__ __align__(16) float hsS[8][128];
  const int r0 = blockIdx.x * 8;
  const int tid = threadIdx.x;
  for (int i = tid; i < 8 * 128; i += 512) ((float*)hsS)[i] = hs1[(size_t)r0 * 128 + i];
  __syncthreads();
  float acc[8] = {0.f, 0.f, 0.f, 0.f, 0.f, 0.f, 0.f, 0.f};
#pragma unroll 4
  for (int k4 = 0; k4 < 32; ++k4) {
    float w0 = wih1T[(4 * k4 + 0) * 512 + tid];
    float w1v = wih1T[(4 * k4 + 1) * 512 + tid];
    float w2v = wih1T[(4 * k4 + 2) * 512 + tid];
    float w3v = wih1T[(4 * k4 + 3) * 512 + tid];
#pragma unroll
    for (int i = 0; i < 8; ++i) {
      float4 h = *(const float4*)(&hsS[i][4 * k4]);
      acc[i] += h.x * w0 + h.y * w1v + h.z * w2v + h.w * w3v;
    }
  }
#pragma unroll
  for (int i = 0; i < 8; ++i) xg1[((size_t)(r0 + i)) * 512 + tid] = acc[i];
}

// ---------------------------------------------------------------------------
// Kernel 6: LSTM layer 1 + FC tail. 32 blocks x 512 thr; whh1 row in VGPRs.
// ---------------------------------------------------------------------------
__global__ __launch_bounds__(512) void k_lstm1(
    const float* __restrict__ xg1, const float* __restrict__ whh1T,
    const float* __restrict__ fc1, const float* __restrict__ fc2,
    const int* __restrict__ lengths, float* __restrict__ out) {
  __shared__ __align__(16) float h1s[H_];
  __shared__ float gs[512];
  __shared__ float tmp10[10];
  const int b = blockIdx.x;
  const int tid = threadIdx.x;
  float w[128];
#pragma unroll
  for (int k = 0; k < 128; ++k) w[k] = whh1T[k * 512 + tid];
  if (tid < H_) h1s[tid] = 0.f;
  float c = 0.f;
  const int len = lengths[b];
  __syncthreads();
  for (int t = 0; t < len; ++t) {
    float a0 = xg1[((size_t)(b * T_ + t)) * 512 + tid];
    float a1 = 0.f;
#pragma unroll
    for (int k4 = 0; k4 < 32; k4 += 2) {
      float4 h = *(const float4*)(h1s + 4 * k4);
      a0 += h.x * w[4 * k4] + h.y * w[4 * k4 + 1] + h.z * w[4 * k4 + 2] + h.w * w[4 * k4 + 3];
      float4 h2 = *(const float4*)(h1s + 4 * k4 + 4);
      a1 += h2.x * w[4 * k4 + 4] + h2.y * w[4 * k4 + 5] + h2.z * w[4 * k4 + 6] + h2.w * w[4 * k4 + 7];
    }
    gs[tid] = a0 + a1;
    __syncthreads();
    if (tid < H_) {
      float ig = sigmoidf_(gs[tid]);
      float fg = sigmoidf_(gs[H_ + tid]);
      float gg = tanhf(gs[2 * H_ + tid]);
      float og = sigmoidf_(gs[3 * H_ + tid]);
      c = fg * c + ig * gg;
      float hn = og * tanhf(c);
      h1s[tid] = hn;
    }
    __syncthreads();
  }
  if (tid < 10) {
    const float* fr = fc1 + tid * H_;
    float s = 0.f;
#pragma unroll 4
    for (int k = 0; k < H_; ++k) s += h1s[k] * fr[k];
    tmp10[tid] = leakyf(s);
  }
  __syncthreads();
  if (tid < 2) {
    const float* fr = fc2 + tid * 10;
    float s = 0.f;
#pragma unroll
    for (int j = 0; j < 10; ++j) s += tmp10[j] * fr[j];
    out[b * 2 + tid] = leakyf(s);
  }
}

extern "C" void kernel_launch(void* const* d_in, const int* in_sizes, int n_in,
                              void* d_out, int out_size, void* d_ws, size_t ws_size,
                              hipStream_t stream) {
  const float* X = (const float*)d_in[0];
  const int* lengths = (const int*)d_in[1];
  const float* w1 = (const float*)d_in[2];
  const float* w2 = (const float*)d_in[3];
  const float* w3 = (const float*)d_in[4];
  const float* linw = (const float*)d_in[5];
  const float* wih0 = (const float*)d_in[6];
  const float* whh0 = (const float*)d_in[7];
  const float* wih1 = (const float*)d_in[8];
  const float* whh1 = (const float*)d_in[9];
  const float* fc1 = (const float*)d_in[10];
  const float* fc2 = (const float*)d_in[11];

  float* wsf = (float*)d_ws;
  // conv phase: conv2o occupies [0, 10813440) floats; xg0 lives above it.
  float* conv2o = wsf;                    // 2048*32*165 = 10,813,440 floats
  float* xg0 = wsf + 10813440;            // 2048*512 floats
  // post-conv phase (conv2o dead after k_conv3lin): alias its region
  float* whh0T = wsf;                     // 65536
  float* wih1T = wsf + 65536;             // 65536
  float* whh1T = wsf + 131072;            // 65536
  float* hs1 = wsf + 196608;              // 32*64*128 = 262144
  float* xg1 = wsf + 458752;              // 2048*512 = 1,048,576

  k_conv12<<<2048, 192, 0, stream>>>(X, w1, w2, conv2o);
  k_conv3lin<<<1024, 512, 0, stream>>>(conv2o, w3, linw, wih0, xg0);
  k_tr<<<64, 256, 0, stream>>>(whh0, whh0T);
  k_tr<<<64, 256, 0, stream>>>(wih1, wih1T);
  k_tr<<<64, 256, 0, stream>>>(whh1, whh1T);
  k_lstm0<<<32, 512, 0, stream>>>(xg0, whh0T, lengths, hs1);
  k_xg1<<<256, 512, 0, stream>>>(hs1, wih1T, xg1);
  k_lstm1<<<32, 512, 0, stream>>>(xg1, whh1T, fc1, fc2, lengths, (float*)d_out);
}

// Round 3
// 793.784 us; speedup vs baseline: 3.5692x; 1.8137x over previous
//
#include <hip/hip_runtime.h>
#include <hip/hip_bf16.h>

#define B_ 32
#define T_ 64
#define H_ 128
#define L2OUT 165
#define L3OUT 54
#define FLAT_ 1728

__device__ __forceinline__ float leakyf(float v) { return v > 0.f ? v : 0.01f * v; }
__device__ __forceinline__ float sigmoidf_(float v) { return 1.f / (1.f + expf(-v)); }

// ---------------------------------------------------------------------------
// Kernel 1: fused conv1+conv2. One block per n (2048 blocks, 256 threads).
// c1 chunked by 8. LDS = 6016 + 16384 + 13312 = 35712 B -> 4 blocks/CU (50%).
// 224 active threads in conv2: 16 c2-groups (2 c2) x 14 l2-groups (12 l2).
// All LDS reads conflict-free or 2-way (free); windows 16B-aligned.
// ---------------------------------------------------------------------------
__global__ __launch_bounds__(256) void k_conv12(
    const float* __restrict__ X, const float* __restrict__ w1,
    const float* __restrict__ w2, float* __restrict__ c2out) {
  __shared__ __align__(16) float Xs[1504];
  __shared__ __align__(16) float s1[8][512];   // conv1 chunk [c1l][pos]
  __shared__ float ws2[8][32 * 13];            // [c1l][c2*13+k] (13-pad rows)

  const int n = blockIdx.x;
  const int tid = threadIdx.x;

  const float* Xn = X + n * 1500;
  for (int i = tid; i < 1500; i += 256) Xs[i] = Xn[i];

  const int act = (tid < 224);
  const int c2g = tid / 14;        // 0..15
  const int l2g = tid - c2g * 14;  // 0..13

  float acc[2][12];
#pragma unroll
  for (int a = 0; a < 2; ++a)
#pragma unroll
    for (int j = 0; j < 12; ++j) acc[a][j] = 0.f;

  for (int cc = 0; cc < 16; ++cc) {  // 16 chunks of 8 c1
    __syncthreads();
    // stage w2 chunk
    for (int d = tid; d < 1280; d += 256) {
      int c1l = d / 160;
      int r = d - c1l * 160;
      int c2 = r / 5;
      int k = r - c2 * 5;
      ws2[c1l][c2 * 13 + k] = w2[c2 * 640 + (cc * 8 + c1l) * 5 + k];
    }
    // conv1 chunk: 8 c1l x 125 groups of 4 positions
    for (int d = tid; d < 1000; d += 256) {
      int c1l = d / 125;
      int pg = d - c1l * 125;
      const float* wr = w1 + (cc * 8 + c1l) * 5;
      float w0 = wr[0], wv1 = wr[1], wv2 = wr[2], wv3 = wr[3], wv4 = wr[4];
      float4 x0 = *(const float4*)(Xs + 12 * pg);
      float4 x1 = *(const float4*)(Xs + 12 * pg + 4);
      float4 x2 = *(const float4*)(Xs + 12 * pg + 8);
      float4 x3 = *(const float4*)(Xs + 12 * pg + 12);
      float xw[16] = {x0.x, x0.y, x0.z, x0.w, x1.x, x1.y, x1.z, x1.w,
                      x2.x, x2.y, x2.z, x2.w, x3.x, x3.y, x3.z, x3.w};
      float4 o;
      o.x = leakyf(xw[0] * w0 + xw[1] * wv1 + xw[2] * wv2 + xw[3] * wv3 + xw[4] * wv4);
      o.y = leakyf(xw[3] * w0 + xw[4] * wv1 + xw[5] * wv2 + xw[6] * wv3 + xw[7] * wv4);
      o.z = leakyf(xw[6] * w0 + xw[7] * wv1 + xw[8] * wv2 + xw[9] * wv3 + xw[10] * wv4);
      o.w = leakyf(xw[9] * w0 + xw[10] * wv1 + xw[11] * wv2 + xw[12] * wv3 + xw[13] * wv4);
      *(float4*)(&s1[c1l][4 * pg]) = o;
    }
    __syncthreads();
    if (act) {
      for (int c1l = 0; c1l < 8; ++c1l) {
        const float* srow = &s1[c1l][36 * l2g];  // 16B-aligned
        float xw[40];
#pragma unroll
        for (int q = 0; q < 10; ++q) {
          float4 v = *(const float4*)(srow + 4 * q);
          xw[4 * q] = v.x; xw[4 * q + 1] = v.y; xw[4 * q + 2] = v.z; xw[4 * q + 3] = v.w;
        }
#pragma unroll
        for (int cc2 = 0; cc2 < 2; ++cc2) {
          const float* wp = &ws2[c1l][(c2g * 2 + cc2) * 13];
          float b0 = wp[0], b1 = wp[1], b2 = wp[2], b3 = wp[3], b4 = wp[4];
#pragma unroll
          for (int j = 0; j < 12; ++j) {
            acc[cc2][j] += xw[3 * j] * b0 + xw[3 * j + 1] * b1 +
                           xw[3 * j + 2] * b2 + xw[3 * j + 3] * b3 +
                           xw[3 * j + 4] * b4;
          }
        }
      }
    }
  }
  if (act) {
#pragma unroll
    for (int cc2 = 0; cc2 < 2; ++cc2) {
      int c2 = c2g * 2 + cc2;
#pragma unroll
      for (int j = 0; j < 12; ++j) {
        int l2 = l2g * 12 + j;
        if (l2 < L2OUT) c2out[((size_t)n * 32 + c2) * L2OUT + l2] = leakyf(acc[cc2][j]);
      }
    }
  }
}

// ---------------------------------------------------------------------------
// Kernel 2: fused conv3 + linear + xg0. One block per n (2048 blocks, 256 thr).
// All dots are thread-private (no shuffles); weights staged in LDS.
// LDS = 22528 + 21632 + 6944 + 800 + 400 = 52304 B -> 3 blocks/CU.
// ---------------------------------------------------------------------------
__global__ __launch_bounds__(256) void k_conv3fe(
    const float* __restrict__ c2o, const float* __restrict__ w3,
    const float* __restrict__ linw, const float* __restrict__ wih0,
    float* __restrict__ xg0) {
  __shared__ __align__(16) float s2[32][176];   // conv2 rows (pad 176)
  __shared__ float w3s[32][169];                // w3 rows (pad 169: distinct banks)
  __shared__ __align__(16) float s3[1736];
  __shared__ float fepart[100][2];
  __shared__ __align__(16) float fe[100];

  const int n = blockIdx.x;
  const int tid = threadIdx.x;

  const float* src = c2o + (size_t)n * 5280;
  for (int i = tid; i < 5280; i += 256) {
    int c2 = i / 165;
    int l2 = i - c2 * 165;
    s2[c2][l2] = src[i];
  }
  for (int i = tid; i < 5120; i += 256) {
    int c3 = i / 160;
    int r = i - c3 * 160;
    w3s[c3][r] = w3[i];
  }
  __syncthreads();

  // conv3: 224 threads = 32 c3 x 7 l3-groups of 8
  if (tid < 224) {
    const int c3 = tid / 7;
    const int l3g = tid - c3 * 7;
    float a8[8] = {0.f, 0.f, 0.f, 0.f, 0.f, 0.f, 0.f, 0.f};
    for (int c2 = 0; c2 < 32; ++c2) {
      const float* sp = &s2[c2][24 * l3g];  // 16B-aligned
      float xw[28];
#pragma unroll
      for (int q = 0; q < 7; ++q) {
        float4 v = *(const float4*)(sp + 4 * q);
        xw[4 * q] = v.x; xw[4 * q + 1] = v.y; xw[4 * q + 2] = v.z; xw[4 * q + 3] = v.w;
      }
      const float* wp = &w3s[c3][c2 * 5];
      float b0 = wp[0], b1 = wp[1], b2 = wp[2], b3 = wp[3], b4 = wp[4];
#pragma unroll
      for (int j = 0; j < 8; ++j) {
        a8[j] += xw[3 * j] * b0 + xw[3 * j + 1] * b1 + xw[3 * j + 2] * b2 +
                 xw[3 * j + 3] * b3 + xw[3 * j + 4] * b4;
      }
    }
#pragma unroll
    for (int j = 0; j < 8; ++j) {
      int l3 = l3g * 8 + j;
      if (l3 < L3OUT) s3[c3 * L3OUT + l3] = leakyf(a8[j]);
    }
  }
  __syncthreads();

  // fe: 200 threads, each a half-dot of 864 (float4), combine via LDS
  if (tid < 200) {
    const int j = tid >> 1, h = tid & 1;
    const float* wr = linw + (size_t)j * FLAT_ + h * 864;
    const float* sp = s3 + h * 864;
    float p = 0.f;
    for (int q = 0; q < 216; ++q) {
      float4 wv = ((const float4*)wr)[q];
      float4 sv = ((const float4*)sp)[q];
      p += wv.x * sv.x + wv.y * sv.y + wv.z * sv.z + wv.w * sv.w;
    }
    fepart[j][h] = p;
  }
  __syncthreads();
  if (tid < 100) fe[tid] = fepart[tid][0] + fepart[tid][1];
  __syncthreads();

  // xg0: thread computes outputs tid and tid+256 (dot of 100, float4)
  float o0 = 0.f, o1 = 0.f;
  const float* wr0 = wih0 + (size_t)tid * 100;
  const float* wr1 = wih0 + ((size_t)tid + 256) * 100;
#pragma unroll 5
  for (int q = 0; q < 25; ++q) {
    float4 a = ((const float4*)wr0)[q];
    float4 b = ((const float4*)wr1)[q];
    float4 f = ((const float4*)fe)[q];
    o0 += a.x * f.x + a.y * f.y + a.z * f.z + a.w * f.w;
    o1 += b.x * f.x + b.y * f.y + b.z * f.z + b.w * f.w;
  }
  xg0[(size_t)n * 512 + tid] = o0;
  xg0[(size_t)n * 512 + tid + 256] = o1;
}

// ---------------------------------------------------------------------------
// Kernel 3: tiled transpose of the 3 recurrent weight mats [512x128]->[128x512]
// 48 blocks (3 mats x 8 jt x 2 kt), 256 threads, LDS 64x65 tile.
// ---------------------------------------------------------------------------
__global__ __launch_bounds__(256) void k_tr_all(
    const float* __restrict__ s0, const float* __restrict__ s1_,
    const float* __restrict__ s2_, float* __restrict__ d0,
    float* __restrict__ d1, float* __restrict__ d2) {
  __shared__ float tile[64][65];
  const int bid = blockIdx.x;
  const int m = bid >> 4, t = bid & 15;
  const int jt = t >> 1, kt = t & 1;
  const float* src = (m == 0) ? s0 : ((m == 1) ? s1_ : s2_);
  float* dst = (m == 0) ? d0 : ((m == 1) ? d1 : d2);
  const int c = threadIdx.x & 63, r0 = threadIdx.x >> 6;
#pragma unroll
  for (int q = 0; q < 16; ++q) {
    int r = r0 + 4 * q;
    tile[r][c] = src[(jt * 64 + r) * 128 + kt * 64 + c];
  }
  __syncthreads();
#pragma unroll
  for (int q = 0; q < 16; ++q) {
    int r = r0 + 4 * q;
    dst[(kt * 64 + r) * 512 + jt * 64 + c] = tile[c][r];
  }
}

// ---------------------------------------------------------------------------
// Kernel 4: LSTM layer 0. 32 blocks x 512 thr; whh0 row held in 128 VGPRs.
// ---------------------------------------------------------------------------
__global__ __launch_bounds__(512) void k_lstm0(
    const float* __restrict__ xg0, const float* __restrict__ whh0T,
    const int* __restrict__ lengths, float* __restrict__ hs1) {
  __shared__ __align__(16) float h0s[H_];
  __shared__ float gs[512];
  const int b = blockIdx.x;
  const int tid = threadIdx.x;
  float w[128];
#pragma unroll
  for (int k = 0; k < 128; ++k) w[k] = whh0T[k * 512 + tid];
  if (tid < H_) h0s[tid] = 0.f;
  float c = 0.f;
  const int len = lengths[b];
  __syncthreads();
  for (int t = 0; t < len; ++t) {
    float a0 = xg0[((size_t)(b * T_ + t)) * 512 + tid];
    float a1 = 0.f;
#pragma unroll
    for (int k4 = 0; k4 < 32; k4 += 2) {
      float4 h = *(const float4*)(h0s + 4 * k4);
      a0 += h.x * w[4 * k4] + h.y * w[4 * k4 + 1] + h.z * w[4 * k4 + 2] + h.w * w[4 * k4 + 3];
      float4 h2 = *(const float4*)(h0s + 4 * k4 + 4);
      a1 += h2.x * w[4 * k4 + 4] + h2.y * w[4 * k4 + 5] + h2.z * w[4 * k4 + 6] + h2.w * w[4 * k4 + 7];
    }
    gs[tid] = a0 + a1;
    __syncthreads();
    if (tid < H_) {
      float ig = sigmoidf_(gs[tid]);
      float fg = sigmoidf_(gs[H_ + tid]);
      float gg = tanhf(gs[2 * H_ + tid]);
      float og = sigmoidf_(gs[3 * H_ + tid]);
      c = fg * c + ig * gg;
      float hn = og * tanhf(c);
      h0s[tid] = hn;
      hs1[((size_t)(b * T_ + t)) * H_ + tid] = hn;
    }
    __syncthreads();
  }
}

// ---------------------------------------------------------------------------
// Kernel 5: xg1 = hs1 @ wih1^T. 256 blocks x 512 thr, 8 rows per block.
// ---------------------------------------------------------------------------
__global__ __launch_bounds__(512) void k_xg1(
    const float* __restrict__ hs1, const float* __restrict__ wih1T,
    float* __restrict__ xg1) {
  __shared__ __align__(16) float hsS[8][128];
  const int r0 = blockIdx.x * 8;
  const int tid = threadIdx.x;
  for (int i = tid; i < 8 * 128; i += 512) ((float*)hsS)[i] = hs1[(size_t)r0 * 128 + i];
  __syncthreads();
  float acc[8] = {0.f, 0.f, 0.f, 0.f, 0.f, 0.f, 0.f, 0.f};
#pragma unroll 4
  for (int k4 = 0; k4 < 32; ++k4) {
    float w0 = wih1T[(4 * k4 + 0) * 512 + tid];
    float w1v = wih1T[(4 * k4 + 1) * 512 + tid];
    float w2v = wih1T[(4 * k4 + 2) * 512 + tid];
    float w3v = wih1T[(4 * k4 + 3) * 512 + tid];
#pragma unroll
    for (int i = 0; i < 8; ++i) {
      float4 h = *(const float4*)(&hsS[i][4 * k4]);
      acc[i] += h.x * w0 + h.y * w1v + h.z * w2v + h.w * w3v;
    }
  }
#pragma unroll
  for (int i = 0; i < 8; ++i) xg1[((size_t)(r0 + i)) * 512 + tid] = acc[i];
}

// ---------------------------------------------------------------------------
// Kernel 6: LSTM layer 1 + FC tail. 32 blocks x 512 thr.
// ---------------------------------------------------------------------------
__global__ __launch_bounds__(512) void k_lstm1(
    const float* __restrict__ xg1, const float* __restrict__ whh1T,
    const float* __restrict__ fc1, const float* __restrict__ fc2,
    const int* __restrict__ lengths, float* __restrict__ out) {
  __shared__ __align__(16) float h1s[H_];
  __shared__ float gs[512];
  __shared__ float tmp10[10];
  const int b = blockIdx.x;
  const int tid = threadIdx.x;
  float w[128];
#pragma unroll
  for (int k = 0; k < 128; ++k) w[k] = whh1T[k * 512 + tid];
  if (tid < H_) h1s[tid] = 0.f;
  float c = 0.f;
  const int len = lengths[b];
  __syncthreads();
  for (int t = 0; t < len; ++t) {
    float a0 = xg1[((size_t)(b * T_ + t)) * 512 + tid];
    float a1 = 0.f;
#pragma unroll
    for (int k4 = 0; k4 < 32; k4 += 2) {
      float4 h = *(const float4*)(h1s + 4 * k4);
      a0 += h.x * w[4 * k4] + h.y * w[4 * k4 + 1] + h.z * w[4 * k4 + 2] + h.w * w[4 * k4 + 3];
      float4 h2 = *(const float4*)(h1s + 4 * k4 + 4);
      a1 += h2.x * w[4 * k4 + 4] + h2.y * w[4 * k4 + 5] + h2.z * w[4 * k4 + 6] + h2.w * w[4 * k4 + 7];
    }
    gs[tid] = a0 + a1;
    __syncthreads();
    if (tid < H_) {
      float ig = sigmoidf_(gs[tid]);
      float fg = sigmoidf_(gs[H_ + tid]);
      float gg = tanhf(gs[2 * H_ + tid]);
      float og = sigmoidf_(gs[3 * H_ + tid]);
      c = fg * c + ig * gg;
      float hn = og * tanhf(c);
      h1s[tid] = hn;
    }
    __syncthreads();
  }
  if (tid < 10) {
    const float* fr = fc1 + tid * H_;
    float s = 0.f;
#pragma unroll 4
    for (int k = 0; k < H_; ++k) s += h1s[k] * fr[k];
    tmp10[tid] = leakyf(s);
  }
  __syncthreads();
  if (tid < 2) {
    const float* fr = fc2 + tid * 10;
    float s = 0.f;
#pragma unroll
    for (int j = 0; j < 10; ++j) s += tmp10[j] * fr[j];
    out[b * 2 + tid] = leakyf(s);
  }
}

extern "C" void kernel_launch(void* const* d_in, const int* in_sizes, int n_in,
                              void* d_out, int out_size, void* d_ws, size_t ws_size,
                              hipStream_t stream) {
  const float* X = (const float*)d_in[0];
  const int* lengths = (const int*)d_in[1];
  const float* w1 = (const float*)d_in[2];
  const float* w2 = (const float*)d_in[3];
  const float* w3 = (const float*)d_in[4];
  const float* linw = (const float*)d_in[5];
  const float* wih0 = (const float*)d_in[6];
  const float* whh0 = (const float*)d_in[7];
  const float* wih1 = (const float*)d_in[8];
  const float* whh1 = (const float*)d_in[9];
  const float* fc1 = (const float*)d_in[10];
  const float* fc2 = (const float*)d_in[11];

  float* wsf = (float*)d_ws;
  // conv phase
  float* conv2o = wsf;                 // 2048*32*165 = 10,813,440 floats
  float* xg0 = wsf + 10813440;         // 2048*512
  // post-conv phase (conv2o region dead after k_conv3fe)
  float* whh0T = wsf;                  // 65536
  float* wih1T = wsf + 65536;          // 65536
  float* whh1T = wsf + 131072;         // 65536
  float* hs1 = wsf + 196608;           // 262144
  float* xg1 = wsf + 458752;           // 1,048,576

  k_conv12<<<2048, 256, 0, stream>>>(X, w1, w2, conv2o);
  k_conv3fe<<<2048, 256, 0, stream>>>(conv2o, w3, linw, wih0, xg0);
  k_tr_all<<<48, 256, 0, stream>>>(whh0, wih1, whh1, whh0T, wih1T, whh1T);
  k_lstm0<<<32, 512, 0, stream>>>(xg0, whh0T, lengths, hs1);
  k_xg1<<<256, 512, 0, stream>>>(hs1, wih1T, xg1);
  k_lstm1<<<32, 512, 0, stream>>>(xg1, whh1T, fc1, fc2, lengths, (float*)d_out);
}

// Round 4
// 705.946 us; speedup vs baseline: 4.0133x; 1.1244x over previous
//
#include <hip/hip_runtime.h>
#include <hip/hip_bf16.h>

#define B_ 32
#define T_ 64
#define H_ 128
#define L2OUT 165
#define L3OUT 54
#define FLAT_ 1728

__device__ __forceinline__ float leakyf(float v) { return v > 0.f ? v : 0.01f * v; }
__device__ __forceinline__ float sigmoidf_(float v) { return 1.f / (1.f + expf(-v)); }

// ---------------------------------------------------------------------------
// Kernel 1: fused conv1+conv2 v3. One block per n (2048 blocks, 192 threads).
// Lane map: tid = l2g*4 + c2g  -> 48 l2-groups (4 l2 each) x 4 c2-groups
// (8 c2 each). Per c1-step each wave issues only 4 window b128 (16 distinct
// addrs, 4-way broadcast) + 10 weight b128 (4 distinct addrs) -> LDS-pipe
// load ~2.3x lower than v2. All dots are fmaf chains (5 VALU / 5 FMA).
// LDS = 6016 + 16384 + 5120 = 27.5 KB -> 5 blocks/CU.
// ---------------------------------------------------------------------------
__global__ __launch_bounds__(192, 2) void k_conv12(
    const float* __restrict__ X, const float* __restrict__ w1,
    const float* __restrict__ w2, float* __restrict__ c2out) {
  __shared__ __align__(16) float Xs[1504];
  __shared__ __align__(16) float s1[8 * 512];      // [c1l][512]
  __shared__ __align__(16) float ws2[8 * 4 * 40];  // [c1l][c2g][c2i*5+k]

  const int n = blockIdx.x;
  const int tid = threadIdx.x;
  const int l2g = tid >> 2;  // 0..47 (42 active)
  const int c2g = tid & 3;   // 0..3

  const float* Xn = X + n * 1500;
  for (int i = tid; i < 1500; i += 192) Xs[i] = Xn[i];
  if (tid < 4) Xs[1500 + tid] = 0.f;

  const int l2gc = (l2g < 42) ? l2g : 41;  // clamp idle lanes (LDS safety)

  float acc[8][4];
#pragma unroll
  for (int a = 0; a < 8; ++a)
#pragma unroll
    for (int j = 0; j < 4; ++j) acc[a][j] = 0.f;

  for (int cc = 0; cc < 16; ++cc) {  // 16 chunks of 8 c1
    __syncthreads();                 // previous chunk fully consumed
    // stage w2 chunk as [c1l][c2g][40]
    for (int d = tid; d < 1280; d += 192) {
      int c1l = d / 160;
      int r = d - c1l * 160;
      int g = r / 40;
      int q = r - g * 40;
      int c2i = q / 5;
      int k = q - c2i * 5;
      ws2[(c1l * 4 + g) * 40 + q] = w2[(g * 8 + c2i) * 640 + (cc * 8 + c1l) * 5 + k];
    }
    // conv1 chunk: 8 c1l x 125 pg; c1l = d&7 so Xs reads broadcast 8-wide
    for (int d = tid; d < 1000; d += 192) {
      int c1l = d & 7;
      int pg = d >> 3;
      const float* wr = w1 + (cc * 8 + c1l) * 5;
      float b0 = wr[0], b1 = wr[1], b2 = wr[2], b3 = wr[3], b4 = wr[4];
      const float* xp = Xs + 12 * pg;
      float4 x0 = *(const float4*)(xp);
      float4 x1 = *(const float4*)(xp + 4);
      float4 x2 = *(const float4*)(xp + 8);
      float4 x3 = *(const float4*)(xp + 12);
      float xv[16] = {x0.x, x0.y, x0.z, x0.w, x1.x, x1.y, x1.z, x1.w,
                      x2.x, x2.y, x2.z, x2.w, x3.x, x3.y, x3.z, x3.w};
      float4 o;
      o.x = leakyf(fmaf(xv[4], b4, fmaf(xv[3], b3, fmaf(xv[2], b2, fmaf(xv[1], b1, xv[0] * b0)))));
      o.y = leakyf(fmaf(xv[7], b4, fmaf(xv[6], b3, fmaf(xv[5], b2, fmaf(xv[4], b1, xv[3] * b0)))));
      o.z = leakyf(fmaf(xv[10], b4, fmaf(xv[9], b3, fmaf(xv[8], b2, fmaf(xv[7], b1, xv[6] * b0)))));
      o.w = leakyf(fmaf(xv[13], b4, fmaf(xv[12], b3, fmaf(xv[11], b2, fmaf(xv[10], b1, xv[9] * b0)))));
      *(float4*)(s1 + c1l * 512 + 4 * pg) = o;
    }
    __syncthreads();
    // conv2 accumulate over this chunk
#pragma unroll 2
    for (int c1l = 0; c1l < 8; ++c1l) {
      const float4* wv4 = (const float4*)(ws2 + (c1l * 4 + c2g) * 40);
      float w[40];
#pragma unroll
      for (int q = 0; q < 10; ++q) {
        float4 t = wv4[q];
        w[4 * q] = t.x; w[4 * q + 1] = t.y; w[4 * q + 2] = t.z; w[4 * q + 3] = t.w;
      }
      const float4* xv4 = (const float4*)(s1 + c1l * 512 + 12 * l2gc);
      float x[16];
#pragma unroll
      for (int q = 0; q < 4; ++q) {
        float4 t = xv4[q];
        x[4 * q] = t.x; x[4 * q + 1] = t.y; x[4 * q + 2] = t.z; x[4 * q + 3] = t.w;
      }
#pragma unroll
      for (int c2i = 0; c2i < 8; ++c2i) {
        const int wb = c2i * 5;
#pragma unroll
        for (int j = 0; j < 4; ++j) {
          float a = acc[c2i][j];
          a = fmaf(x[3 * j + 0], w[wb + 0], a);
          a = fmaf(x[3 * j + 1], w[wb + 1], a);
          a = fmaf(x[3 * j + 2], w[wb + 2], a);
          a = fmaf(x[3 * j + 3], w[wb + 3], a);
          a = fmaf(x[3 * j + 4], w[wb + 4], a);
          acc[c2i][j] = a;
        }
      }
    }
  }
  // write out (scalar stores; rows stride 165)
  if (l2g < 42) {
#pragma unroll
    for (int c2i = 0; c2i < 8; ++c2i) {
      int c2 = c2g * 8 + c2i;
      float* orow = c2out + ((size_t)n * 32 + c2) * L2OUT;
#pragma unroll
      for (int j = 0; j < 4; ++j) {
        int l2 = 4 * l2g + j;
        if (l2 < L2OUT) orow[l2] = leakyf(acc[c2i][j]);
      }
    }
  }
}

// ---------------------------------------------------------------------------
// Kernel 2: fused conv3 + linear + xg0. One block per n (2048 blocks, 256 thr).
// fmaf chains with independent per-component accumulators.
// ---------------------------------------------------------------------------
__global__ __launch_bounds__(256) void k_conv3fe(
    const float* __restrict__ c2o, const float* __restrict__ w3,
    const float* __restrict__ linw, const float* __restrict__ wih0,
    float* __restrict__ xg0) {
  __shared__ __align__(16) float s2[32][176];   // conv2 rows (pad 176)
  __shared__ float w3s[32][169];                // w3 rows (pad 169)
  __shared__ __align__(16) float s3[1736];
  __shared__ float fepart[100][2];
  __shared__ __align__(16) float fe[100];

  const int n = blockIdx.x;
  const int tid = threadIdx.x;

  const float* src = c2o + (size_t)n * 5280;
  for (int i = tid; i < 5280; i += 256) {
    int c2 = i / 165;
    int l2 = i - c2 * 165;
    s2[c2][l2] = src[i];
  }
  for (int i = tid; i < 5120; i += 256) {
    int c3 = i / 160;
    int r = i - c3 * 160;
    w3s[c3][r] = w3[i];
  }
  __syncthreads();

  // conv3: 224 threads = 32 c3 x 7 l3-groups of 8
  if (tid < 224) {
    const int c3 = tid / 7;
    const int l3g = tid - c3 * 7;
    float a8[8] = {0.f, 0.f, 0.f, 0.f, 0.f, 0.f, 0.f, 0.f};
    for (int c2 = 0; c2 < 32; ++c2) {
      const float* sp = &s2[c2][24 * l3g];
      float xw[28];
#pragma unroll
      for (int q = 0; q < 7; ++q) {
        float4 v = *(const float4*)(sp + 4 * q);
        xw[4 * q] = v.x; xw[4 * q + 1] = v.y; xw[4 * q + 2] = v.z; xw[4 * q + 3] = v.w;
      }
      const float* wp = &w3s[c3][c2 * 5];
      float b0 = wp[0], b1 = wp[1], b2 = wp[2], b3 = wp[3], b4 = wp[4];
#pragma unroll
      for (int j = 0; j < 8; ++j) {
        float a = a8[j];
        a = fmaf(xw[3 * j + 0], b0, a);
        a = fmaf(xw[3 * j + 1], b1, a);
        a = fmaf(xw[3 * j + 2], b2, a);
        a = fmaf(xw[3 * j + 3], b3, a);
        a = fmaf(xw[3 * j + 4], b4, a);
        a8[j] = a;
      }
    }
#pragma unroll
    for (int j = 0; j < 8; ++j) {
      int l3 = l3g * 8 + j;
      if (l3 < L3OUT) s3[c3 * L3OUT + l3] = leakyf(a8[j]);
    }
  }
  __syncthreads();

  // fe: 200 threads, each a half-dot of 864; 4 independent fmaf chains
  if (tid < 200) {
    const int j = tid >> 1, h = tid & 1;
    const float4* wr = (const float4*)(linw + (size_t)j * FLAT_ + h * 864);
    const float4* sp = (const float4*)(s3 + h * 864);
    float p0 = 0.f, p1 = 0.f, p2 = 0.f, p3 = 0.f;
#pragma unroll 4
    for (int q = 0; q < 216; ++q) {
      float4 wv = wr[q];
      float4 sv = sp[q];
      p0 = fmaf(wv.x, sv.x, p0);
      p1 = fmaf(wv.y, sv.y, p1);
      p2 = fmaf(wv.z, sv.z, p2);
      p3 = fmaf(wv.w, sv.w, p3);
    }
    fepart[j][h] = (p0 + p1) + (p2 + p3);
  }
  __syncthreads();
  if (tid < 100) fe[tid] = fepart[tid][0] + fepart[tid][1];
  __syncthreads();

  // xg0: thread computes outputs tid and tid+256 (dot of 100)
  float a0 = 0.f, a1 = 0.f, a2 = 0.f, a3 = 0.f;
  float c0 = 0.f, c1 = 0.f, c2v = 0.f, c3v = 0.f;
  const float4* wr0 = (const float4*)(wih0 + (size_t)tid * 100);
  const float4* wr1 = (const float4*)(wih0 + ((size_t)tid + 256) * 100);
#pragma unroll 5
  for (int q = 0; q < 25; ++q) {
    float4 a = wr0[q];
    float4 b = wr1[q];
    float4 f = ((const float4*)fe)[q];
    a0 = fmaf(a.x, f.x, a0); a1 = fmaf(a.y, f.y, a1);
    a2 = fmaf(a.z, f.z, a2); a3 = fmaf(a.w, f.w, a3);
    c0 = fmaf(b.x, f.x, c0); c1 = fmaf(b.y, f.y, c1);
    c2v = fmaf(b.z, f.z, c2v); c3v = fmaf(b.w, f.w, c3v);
  }
  xg0[(size_t)n * 512 + tid] = (a0 + a1) + (a2 + a3);
  xg0[(size_t)n * 512 + tid + 256] = (c0 + c1) + (c2v + c3v);
}

// ---------------------------------------------------------------------------
// Kernel 3: tiled transpose of the 3 recurrent weight mats [512x128]->[128x512]
// ---------------------------------------------------------------------------
__global__ __launch_bounds__(256) void k_tr_all(
    const float* __restrict__ s0, const float* __restrict__ s1_,
    const float* __restrict__ s2_, float* __restrict__ d0,
    float* __restrict__ d1, float* __restrict__ d2) {
  __shared__ float tile[64][65];
  const int bid = blockIdx.x;
  const int m = bid >> 4, t = bid & 15;
  const int jt = t >> 1, kt = t & 1;
  const float* src = (m == 0) ? s0 : ((m == 1) ? s1_ : s2_);
  float* dst = (m == 0) ? d0 : ((m == 1) ? d1 : d2);
  const int c = threadIdx.x & 63, r0 = threadIdx.x >> 6;
#pragma unroll
  for (int q = 0; q < 16; ++q) {
    int r = r0 + 4 * q;
    tile[r][c] = src[(jt * 64 + r) * 128 + kt * 64 + c];
  }
  __syncthreads();
#pragma unroll
  for (int q = 0; q < 16; ++q) {
    int r = r0 + 4 * q;
    dst[(kt * 64 + r) * 512 + jt * 64 + c] = tile[c][r];
  }
}

// ---------------------------------------------------------------------------
// Kernel 4: LSTM layer 0. 32 blocks x 512 thr; whh0 row held in 128 VGPRs.
// ---------------------------------------------------------------------------
__global__ __launch_bounds__(512) void k_lstm0(
    const float* __restrict__ xg0, const float* __restrict__ whh0T,
    const int* __restrict__ lengths, float* __restrict__ hs1) {
  __shared__ __align__(16) float h0s[H_];
  __shared__ float gs[512];
  const int b = blockIdx.x;
  const int tid = threadIdx.x;
  float w[128];
#pragma unroll
  for (int k = 0; k < 128; ++k) w[k] = whh0T[k * 512 + tid];
  if (tid < H_) h0s[tid] = 0.f;
  float c = 0.f;
  const int len = lengths[b];
  __syncthreads();
  for (int t = 0; t < len; ++t) {
    float a0 = xg0[((size_t)(b * T_ + t)) * 512 + tid];
    float a1 = 0.f;
#pragma unroll
    for (int k4 = 0; k4 < 32; k4 += 2) {
      float4 h = *(const float4*)(h0s + 4 * k4);
      a0 += h.x * w[4 * k4] + h.y * w[4 * k4 + 1] + h.z * w[4 * k4 + 2] + h.w * w[4 * k4 + 3];
      float4 h2 = *(const float4*)(h0s + 4 * k4 + 4);
      a1 += h2.x * w[4 * k4 + 4] + h2.y * w[4 * k4 + 5] + h2.z * w[4 * k4 + 6] + h2.w * w[4 * k4 + 7];
    }
    gs[tid] = a0 + a1;
    __syncthreads();
    if (tid < H_) {
      float ig = sigmoidf_(gs[tid]);
      float fg = sigmoidf_(gs[H_ + tid]);
      float gg = tanhf(gs[2 * H_ + tid]);
      float og = sigmoidf_(gs[3 * H_ + tid]);
      c = fg * c + ig * gg;
      float hn = og * tanhf(c);
      h0s[tid] = hn;
      hs1[((size_t)(b * T_ + t)) * H_ + tid] = hn;
    }
    __syncthreads();
  }
}

// ---------------------------------------------------------------------------
// Kernel 5: xg1 = hs1 @ wih1^T. 256 blocks x 512 thr, 8 rows per block.
// ---------------------------------------------------------------------------
__global__ __launch_bounds__(512) void k_xg1(
    const float* __restrict__ hs1, const float* __restrict__ wih1T,
    float* __restrict__ xg1) {
  __shared__ __align__(16) float hsS[8][128];
  const int r0 = blockIdx.x * 8;
  const int tid = threadIdx.x;
  for (int i = tid; i < 8 * 128; i += 512) ((float*)hsS)[i] = hs1[(size_t)r0 * 128 + i];
  __syncthreads();
  float acc[8] = {0.f, 0.f, 0.f, 0.f, 0.f, 0.f, 0.f, 0.f};
#pragma unroll 4
  for (int k4 = 0; k4 < 32; ++k4) {
    float w0 = wih1T[(4 * k4 + 0) * 512 + tid];
    float w1v = wih1T[(4 * k4 + 1) * 512 + tid];
    float w2v = wih1T[(4 * k4 + 2) * 512 + tid];
    float w3v = wih1T[(4 * k4 + 3) * 512 + tid];
#pragma unroll
    for (int i = 0; i < 8; ++i) {
      float4 h = *(const float4*)(&hsS[i][4 * k4]);
      acc[i] += h.x * w0 + h.y * w1v + h.z * w2v + h.w * w3v;
    }
  }
#pragma unroll
  for (int i = 0; i < 8; ++i) xg1[((size_t)(r0 + i)) * 512 + tid] = acc[i];
}

// ---------------------------------------------------------------------------
// Kernel 6: LSTM layer 1 + FC tail. 32 blocks x 512 thr.
// ---------------------------------------------------------------------------
__global__ __launch_bounds__(512) void k_lstm1(
    const float* __restrict__ xg1, const float* __restrict__ whh1T,
    const float* __restrict__ fc1, const float* __restrict__ fc2,
    const int* __restrict__ lengths, float* __restrict__ out) {
  __shared__ __align__(16) float h1s[H_];
  __shared__ float gs[512];
  __shared__ float tmp10[10];
  const int b = blockIdx.x;
  const int tid = threadIdx.x;
  float w[128];
#pragma unroll
  for (int k = 0; k < 128; ++k) w[k] = whh1T[k * 512 + tid];
  if (tid < H_) h1s[tid] = 0.f;
  float c = 0.f;
  const int len = lengths[b];
  __syncthreads();
  for (int t = 0; t < len; ++t) {
    float a0 = xg1[((size_t)(b * T_ + t)) * 512 + tid];
    float a1 = 0.f;
#pragma unroll
    for (int k4 = 0; k4 < 32; k4 += 2) {
      float4 h = *(const float4*)(h1s + 4 * k4);
      a0 += h.x * w[4 * k4] + h.y * w[4 * k4 + 1] + h.z * w[4 * k4 + 2] + h.w * w[4 * k4 + 3];
      float4 h2 = *(const float4*)(h1s + 4 * k4 + 4);
      a1 += h2.x * w[4 * k4 + 4] + h2.y * w[4 * k4 + 5] + h2.z * w[4 * k4 + 6] + h2.w * w[4 * k4 + 7];
    }
    gs[tid] = a0 + a1;
    __syncthreads();
    if (tid < H_) {
      float ig = sigmoidf_(gs[tid]);
      float fg = sigmoidf_(gs[H_ + tid]);
      float gg = tanhf(gs[2 * H_ + tid]);
      float og = sigmoidf_(gs[3 * H_ + tid]);
      c = fg * c + ig * gg;
      float hn = og * tanhf(c);
      h1s[tid] = hn;
    }
    __syncthreads();
  }
  if (tid < 10) {
    const float* fr = fc1 + tid * H_;
    float s = 0.f;
#pragma unroll 4
    for (int k = 0; k < H_; ++k) s += h1s[k] * fr[k];
    tmp10[tid] = leakyf(s);
  }
  __syncthreads();
  if (tid < 2) {
    const float* fr = fc2 + tid * 10;
    float s = 0.f;
#pragma unroll
    for (int j = 0; j < 10; ++j) s += tmp10[j] * fr[j];
    out[b * 2 + tid] = leakyf(s);
  }
}

extern "C" void kernel_launch(void* const* d_in, const int* in_sizes, int n_in,
                              void* d_out, int out_size, void* d_ws, size_t ws_size,
                              hipStream_t stream) {
  const float* X = (const float*)d_in[0];
  const int* lengths = (const int*)d_in[1];
  const float* w1 = (const float*)d_in[2];
  const float* w2 = (const float*)d_in[3];
  const float* w3 = (const float*)d_in[4];
  const float* linw = (const float*)d_in[5];
  const float* wih0 = (const float*)d_in[6];
  const float* whh0 = (const float*)d_in[7];
  const float* wih1 = (const float*)d_in[8];
  const float* whh1 = (const float*)d_in[9];
  const float* fc1 = (const float*)d_in[10];
  const float* fc2 = (const float*)d_in[11];

  float* wsf = (float*)d_ws;
  float* conv2o = wsf;                 // 2048*32*165 = 10,813,440 floats
  float* xg0 = wsf + 10813440;         // 2048*512
  float* whh0T = wsf;                  // aliases dead conv2o region
  float* wih1T = wsf + 65536;
  float* whh1T = wsf + 131072;
  float* hs1 = wsf + 196608;
  float* xg1 = wsf + 458752;

  k_conv12<<<2048, 192, 0, stream>>>(X, w1, w2, conv2o);
  k_conv3fe<<<2048, 256, 0, stream>>>(conv2o, w3, linw, wih0, xg0);
  k_tr_all<<<48, 256, 0, stream>>>(whh0, wih1, whh1, whh0T, wih1T, whh1T);
  k_lstm0<<<32, 512, 0, stream>>>(xg0, whh0T, lengths, hs1);
  k_xg1<<<256, 512, 0, stream>>>(hs1, wih1T, xg1);
  k_lstm1<<<32, 512, 0, stream>>>(xg1, whh1T, fc1, fc2, lengths, (float*)d_out);
}

// Round 5
// 532.403 us; speedup vs baseline: 5.3215x; 1.3260x over previous
//
#include <hip/hip_runtime.h>
#include <hip/hip_bf16.h>

#define B_ 32
#define T_ 64
#define H_ 128
#define L2OUT 165
#define L3OUT 54
#define FLAT_ 1728

typedef __attribute__((ext_vector_type(8))) short bf16x8;
typedef __attribute__((ext_vector_type(4))) float f32x4;

__device__ __forceinline__ float leakyf(float v) { return v > 0.f ? v : 0.01f * v; }
__device__ __forceinline__ float sigmoidf_(float v) { return 1.f / (1.f + expf(-v)); }
__device__ __forceinline__ unsigned int bf16rne(float v) {
  unsigned int b = __float_as_uint(v);
  return (b + 0x7FFFu + ((b >> 16) & 1u)) >> 16;
}

// ---------------------------------------------------------------------------
// Kernel 1: fused conv1 (fp32 VALU) + conv2 (bf16 MFMA, weight hi/lo split).
// One block per n; 256 threads = 4 waves.
// conv1 stored transposed in LDS: Ah[pos][c1-chunk of 32] as bf16 -> the
// MFMA B-fragment (8 contiguous c1) is one ds_read_b128, conflict-free.
// K-step = one filter tap over 32 c1; 5 taps x 4 c1-chunks = 20 K-steps.
// Weights: W2T[c2][tap*32+c1l] split hi+lo bf16 -> 2 MFMA passes kill
// weight rounding; activation bf16 rel err ~0.11% (budget 2%).
// Wave w owns n-tiles {w, w+4, w+8} of 11 (176 l2, >=165 kept).
// LDS = 6016 + 34048 + 2*10752 = 61568 B -> 2 blocks/CU.
// ---------------------------------------------------------------------------
__global__ __launch_bounds__(256) void k_conv12(
    const float* __restrict__ X, const float* __restrict__ w1,
    const float* __restrict__ w2, float* __restrict__ c2out) {
  __shared__ __align__(16) float Xs[1504];
  __shared__ __align__(16) short Ah[532 * 32];   // [pos 0..531][c1l 0..31]
  __shared__ __align__(16) short W2h[32 * 168];  // [c2][tap*32+c1l], pad 168
  __shared__ __align__(16) short W2l[32 * 168];

  const int n = blockIdx.x;
  const int tid = threadIdx.x;
  const int lane = tid & 63;
  const int w = tid >> 6;
  const int l15 = lane & 15;
  const int cg = lane >> 4;

  // stage X (+ zero tail so garbage pos 497..499 stay finite)
  const float* Xn = X + (size_t)n * 1500;
  for (int i = tid; i < 1500; i += 256) Xs[i] = Xn[i];
  if (tid < 4) Xs[1500 + tid] = 0.f;
  // zero Ah pad rows (pos 500..531) once; never overwritten
  {
    unsigned int* A32 = (unsigned int*)(Ah + 500 * 32);
    for (int i = tid; i < 512; i += 256) A32[i] = 0u;
  }

  const int pr = tid & 15;  // c1-pair within chunk (c1 = 2pr, 2pr+1)
  const int po = tid >> 4;  // pos offset 0..15

  f32x4 acc[3][2];
#pragma unroll
  for (int a = 0; a < 3; ++a)
#pragma unroll
    for (int m = 0; m < 2; ++m) acc[a][m] = (f32x4){0.f, 0.f, 0.f, 0.f};

  for (int cc = 0; cc < 4; ++cc) {  // 4 chunks of 32 c1
    __syncthreads();  // previous chunk's MFMA reads complete
    // ---- stage W2T hi/lo for this chunk ----
    for (int d = tid; d < 5120; d += 256) {
      int c2 = d / 160;
      int r = d - c2 * 160;  // tap*32 + c1l
      int tap = r >> 5;
      int c1l = r & 31;
      float wv = w2[c2 * 640 + (cc * 32 + c1l) * 5 + tap];
      unsigned int hb = bf16rne(wv);
      float hf = __uint_as_float(hb << 16);
      unsigned int lb = bf16rne(wv - hf);
      W2h[c2 * 168 + r] = (short)hb;
      W2l[c2 * 168 + r] = (short)lb;
    }
    // ---- conv1 for this chunk (fp32), store bf16 transposed ----
    const float* wA = w1 + (cc * 32 + 2 * pr) * 5;
    float a0 = wA[0], a1 = wA[1], a2 = wA[2], a3 = wA[3], a4 = wA[4];
    float b0 = wA[5], b1 = wA[6], b2 = wA[7], b3 = wA[8], b4 = wA[9];
    unsigned int* Arow = (unsigned int*)Ah;
#pragma unroll 2
    for (int i = 0; i < 32; ++i) {
      int pos = po + 16 * i;
      if (pos < 500) {
        const float* xp = Xs + 3 * pos;
        float x0 = xp[0], x1 = xp[1], x2 = xp[2], x3 = xp[3], x4 = xp[4];
        float vA = fmaf(x4, a4, fmaf(x3, a3, fmaf(x2, a2, fmaf(x1, a1, x0 * a0))));
        float vB = fmaf(x4, b4, fmaf(x3, b3, fmaf(x2, b2, fmaf(x1, b1, x0 * b0))));
        vA = leakyf(vA);
        vB = leakyf(vB);
        Arow[pos * 16 + pr] = bf16rne(vA) | (bf16rne(vB) << 16);
      }
    }
    __syncthreads();
    // ---- MFMA: 5 taps x <=3 n-tiles x 2 m-tiles x (hi+lo) ----
#pragma unroll
    for (int tap = 0; tap < 5; ++tap) {
      const int wcol = tap * 32 + cg * 8;
      bf16x8 ah0 = *(const bf16x8*)(W2h + l15 * 168 + wcol);
      bf16x8 ah1 = *(const bf16x8*)(W2h + (l15 + 16) * 168 + wcol);
      bf16x8 al0 = *(const bf16x8*)(W2l + l15 * 168 + wcol);
      bf16x8 al1 = *(const bf16x8*)(W2l + (l15 + 16) * 168 + wcol);
#pragma unroll
      for (int nti = 0; nti < 3; ++nti) {
        int nt = w + 4 * nti;
        if (nt < 11) {
          bf16x8 bfr = *(const bf16x8*)(Ah + (3 * (nt * 16 + l15) + tap) * 32 + cg * 8);
          acc[nti][0] = __builtin_amdgcn_mfma_f32_16x16x32_bf16(ah0, bfr, acc[nti][0], 0, 0, 0);
          acc[nti][0] = __builtin_amdgcn_mfma_f32_16x16x32_bf16(al0, bfr, acc[nti][0], 0, 0, 0);
          acc[nti][1] = __builtin_amdgcn_mfma_f32_16x16x32_bf16(ah1, bfr, acc[nti][1], 0, 0, 0);
          acc[nti][1] = __builtin_amdgcn_mfma_f32_16x16x32_bf16(al1, bfr, acc[nti][1], 0, 0, 0);
        }
      }
    }
  }
  // ---- epilogue: C/D layout col=lane&15 (l2), row=(lane>>4)*4+reg (c2) ----
#pragma unroll
  for (int nti = 0; nti < 3; ++nti) {
    int nt = w + 4 * nti;
    if (nt < 11) {
      int l2 = nt * 16 + l15;
      if (l2 < L2OUT) {
#pragma unroll
        for (int mt = 0; mt < 2; ++mt) {
#pragma unroll
          for (int r = 0; r < 4; ++r) {
            int c2 = mt * 16 + cg * 4 + r;
            c2out[((size_t)n * 32 + c2) * L2OUT + l2] = leakyf(acc[nti][mt][r]);
          }
        }
      }
    }
  }
}

// ---------------------------------------------------------------------------
// Kernel 2: fused conv3 + linear + xg0. One block per n (2048 blocks, 256 thr).
// (unchanged this round; round-6 target)
// ---------------------------------------------------------------------------
__global__ __launch_bounds__(256) void k_conv3fe(
    const float* __restrict__ c2o, const float* __restrict__ w3,
    const float* __restrict__ linw, const float* __restrict__ wih0,
    float* __restrict__ xg0) {
  __shared__ __align__(16) float s2[32][176];
  __shared__ float w3s[32][169];
  __shared__ __align__(16) float s3[1736];
  __shared__ float fepart[100][2];
  __shared__ __align__(16) float fe[100];

  const int n = blockIdx.x;
  const int tid = threadIdx.x;

  const float* src = c2o + (size_t)n * 5280;
  for (int i = tid; i < 5280; i += 256) {
    int c2 = i / 165;
    int l2 = i - c2 * 165;
    s2[c2][l2] = src[i];
  }
  for (int i = tid; i < 5120; i += 256) {
    int c3 = i / 160;
    int r = i - c3 * 160;
    w3s[c3][r] = w3[i];
  }
  __syncthreads();

  if (tid < 224) {
    const int c3 = tid / 7;
    const int l3g = tid - c3 * 7;
    float a8[8] = {0.f, 0.f, 0.f, 0.f, 0.f, 0.f, 0.f, 0.f};
    for (int c2 = 0; c2 < 32; ++c2) {
      const float* sp = &s2[c2][24 * l3g];
      float xw[28];
#pragma unroll
      for (int q = 0; q < 7; ++q) {
        float4 v = *(const float4*)(sp + 4 * q);
        xw[4 * q] = v.x; xw[4 * q + 1] = v.y; xw[4 * q + 2] = v.z; xw[4 * q + 3] = v.w;
      }
      const float* wp = &w3s[c3][c2 * 5];
      float b0 = wp[0], b1 = wp[1], b2 = wp[2], b3 = wp[3], b4 = wp[4];
#pragma unroll
      for (int j = 0; j < 8; ++j) {
        float a = a8[j];
        a = fmaf(xw[3 * j + 0], b0, a);
        a = fmaf(xw[3 * j + 1], b1, a);
        a = fmaf(xw[3 * j + 2], b2, a);
        a = fmaf(xw[3 * j + 3], b3, a);
        a = fmaf(xw[3 * j + 4], b4, a);
        a8[j] = a;
      }
    }
#pragma unroll
    for (int j = 0; j < 8; ++j) {
      int l3 = l3g * 8 + j;
      if (l3 < L3OUT) s3[c3 * L3OUT + l3] = leakyf(a8[j]);
    }
  }
  __syncthreads();

  if (tid < 200) {
    const int j = tid >> 1, h = tid & 1;
    const float4* wr = (const float4*)(linw + (size_t)j * FLAT_ + h * 864);
    const float4* sp = (const float4*)(s3 + h * 864);
    float p0 = 0.f, p1 = 0.f, p2 = 0.f, p3 = 0.f;
#pragma unroll 4
    for (int q = 0; q < 216; ++q) {
      float4 wv = wr[q];
      float4 sv = sp[q];
      p0 = fmaf(wv.x, sv.x, p0);
      p1 = fmaf(wv.y, sv.y, p1);
      p2 = fmaf(wv.z, sv.z, p2);
      p3 = fmaf(wv.w, sv.w, p3);
    }
    fepart[j][h] = (p0 + p1) + (p2 + p3);
  }
  __syncthreads();
  if (tid < 100) fe[tid] = fepart[tid][0] + fepart[tid][1];
  __syncthreads();

  float a0 = 0.f, a1 = 0.f, a2 = 0.f, a3 = 0.f;
  float c0 = 0.f, c1 = 0.f, c2v = 0.f, c3v = 0.f;
  const float4* wr0 = (const float4*)(wih0 + (size_t)tid * 100);
  const float4* wr1 = (const float4*)(wih0 + ((size_t)tid + 256) * 100);
#pragma unroll 5
  for (int q = 0; q < 25; ++q) {
    float4 a = wr0[q];
    float4 b = wr1[q];
    float4 f = ((const float4*)fe)[q];
    a0 = fmaf(a.x, f.x, a0); a1 = fmaf(a.y, f.y, a1);
    a2 = fmaf(a.z, f.z, a2); a3 = fmaf(a.w, f.w, a3);
    c0 = fmaf(b.x, f.x, c0); c1 = fmaf(b.y, f.y, c1);
    c2v = fmaf(b.z, f.z, c2v); c3v = fmaf(b.w, f.w, c3v);
  }
  xg0[(size_t)n * 512 + tid] = (a0 + a1) + (a2 + a3);
  xg0[(size_t)n * 512 + tid + 256] = (c0 + c1) + (c2v + c3v);
}

// ---------------------------------------------------------------------------
// Kernel 3: tiled transpose of the 3 recurrent weight mats [512x128]->[128x512]
// ---------------------------------------------------------------------------
__global__ __launch_bounds__(256) void k_tr_all(
    const float* __restrict__ s0, const float* __restrict__ s1_,
    const float* __restrict__ s2_, float* __restrict__ d0,
    float* __restrict__ d1, float* __restrict__ d2) {
  __shared__ float tile[64][65];
  const int bid = blockIdx.x;
  const int m = bid >> 4, t = bid & 15;
  const int jt = t >> 1, kt = t & 1;
  const float* src = (m == 0) ? s0 : ((m == 1) ? s1_ : s2_);
  float* dst = (m == 0) ? d0 : ((m == 1) ? d1 : d2);
  const int c = threadIdx.x & 63, r0 = threadIdx.x >> 6;
#pragma unroll
  for (int q = 0; q < 16; ++q) {
    int r = r0 + 4 * q;
    tile[r][c] = src[(jt * 64 + r) * 128 + kt * 64 + c];
  }
  __syncthreads();
#pragma unroll
  for (int q = 0; q < 16; ++q) {
    int r = r0 + 4 * q;
    dst[(kt * 64 + r) * 512 + jt * 64 + c] = tile[c][r];
  }
}

// ---------------------------------------------------------------------------
// Kernel 4: LSTM layer 0. 32 blocks x 512 thr; whh0 row held in 128 VGPRs.
// ---------------------------------------------------------------------------
__global__ __launch_bounds__(512) void k_lstm0(
    const float* __restrict__ xg0, const float* __restrict__ whh0T,
    const int* __restrict__ lengths, float* __restrict__ hs1) {
  __shared__ __align__(16) float h0s[H_];
  __shared__ float gs[512];
  const int b = blockIdx.x;
  const int tid = threadIdx.x;
  float w[128];
#pragma unroll
  for (int k = 0; k < 128; ++k) w[k] = whh0T[k * 512 + tid];
  if (tid < H_) h0s[tid] = 0.f;
  float c = 0.f;
  const int len = lengths[b];
  __syncthreads();
  for (int t = 0; t < len; ++t) {
    float a0 = xg0[((size_t)(b * T_ + t)) * 512 + tid];
    float a1 = 0.f;
#pragma unroll
    for (int k4 = 0; k4 < 32; k4 += 2) {
      float4 h = *(const float4*)(h0s + 4 * k4);
      a0 += h.x * w[4 * k4] + h.y * w[4 * k4 + 1] + h.z * w[4 * k4 + 2] + h.w * w[4 * k4 + 3];
      float4 h2 = *(const float4*)(h0s + 4 * k4 + 4);
      a1 += h2.x * w[4 * k4 + 4] + h2.y * w[4 * k4 + 5] + h2.z * w[4 * k4 + 6] + h2.w * w[4 * k4 + 7];
    }
    gs[tid] = a0 + a1;
    __syncthreads();
    if (tid < H_) {
      float ig = sigmoidf_(gs[tid]);
      float fg = sigmoidf_(gs[H_ + tid]);
      float gg = tanhf(gs[2 * H_ + tid]);
      float og = sigmoidf_(gs[3 * H_ + tid]);
      c = fg * c + ig * gg;
      float hn = og * tanhf(c);
      h0s[tid] = hn;
      hs1[((size_t)(b * T_ + t)) * H_ + tid] = hn;
    }
    __syncthreads();
  }
}

// ---------------------------------------------------------------------------
// Kernel 5: xg1 = hs1 @ wih1^T. 256 blocks x 512 thr, 8 rows per block.
// ---------------------------------------------------------------------------
__global__ __launch_bounds__(512) void k_xg1(
    const float* __restrict__ hs1, const float* __restrict__ wih1T,
    float* __restrict__ xg1) {
  __shared__ __align__(16) float hsS[8][128];
  const int r0 = blockIdx.x * 8;
  const int tid = threadIdx.x;
  for (int i = tid; i < 8 * 128; i += 512) ((float*)hsS)[i] = hs1[(size_t)r0 * 128 + i];
  __syncthreads();
  float acc[8] = {0.f, 0.f, 0.f, 0.f, 0.f, 0.f, 0.f, 0.f};
#pragma unroll 4
  for (int k4 = 0; k4 < 32; ++k4) {
    float w0 = wih1T[(4 * k4 + 0) * 512 + tid];
    float w1v = wih1T[(4 * k4 + 1) * 512 + tid];
    float w2v = wih1T[(4 * k4 + 2) * 512 + tid];
    float w3v = wih1T[(4 * k4 + 3) * 512 + tid];
#pragma unroll
    for (int i = 0; i < 8; ++i) {
      float4 h = *(const float4*)(&hsS[i][4 * k4]);
      acc[i] += h.x * w0 + h.y * w1v + h.z * w2v + h.w * w3v;
    }
  }
#pragma unroll
  for (int i = 0; i < 8; ++i) xg1[((size_t)(r0 + i)) * 512 + tid] = acc[i];
}

// ---------------------------------------------------------------------------
// Kernel 6: LSTM layer 1 + FC tail. 32 blocks x 512 thr.
// ---------------------------------------------------------------------------
__global__ __launch_bounds__(512) void k_lstm1(
    const float* __restrict__ xg1, const float* __restrict__ whh1T,
    const float* __restrict__ fc1, const float* __restrict__ fc2,
    const int* __restrict__ lengths, float* __restrict__ out) {
  __shared__ __align__(16) float h1s[H_];
  __shared__ float gs[512];
  __shared__ float tmp10[10];
  const int b = blockIdx.x;
  const int tid = threadIdx.x;
  float w[128];
#pragma unroll
  for (int k = 0; k < 128; ++k) w[k] = whh1T[k * 512 + tid];
  if (tid < H_) h1s[tid] = 0.f;
  float c = 0.f;
  const int len = lengths[b];
  __syncthreads();
  for (int t = 0; t < len; ++t) {
    float a0 = xg1[((size_t)(b * T_ + t)) * 512 + tid];
    float a1 = 0.f;
#pragma unroll
    for (int k4 = 0; k4 < 32; k4 += 2) {
      float4 h = *(const float4*)(h1s + 4 * k4);
      a0 += h.x * w[4 * k4] + h.y * w[4 * k4 + 1] + h.z * w[4 * k4 + 2] + h.w * w[4 * k4 + 3];
      float4 h2 = *(const float4*)(h1s + 4 * k4 + 4);
      a1 += h2.x * w[4 * k4 + 4] + h2.y * w[4 * k4 + 5] + h2.z * w[4 * k4 + 6] + h2.w * w[4 * k4 + 7];
    }
    gs[tid] = a0 + a1;
    __syncthreads();
    if (tid < H_) {
      float ig = sigmoidf_(gs[tid]);
      float fg = sigmoidf_(gs[H_ + tid]);
      float gg = tanhf(gs[2 * H_ + tid]);
      float og = sigmoidf_(gs[3 * H_ + tid]);
      c = fg * c + ig * gg;
      float hn = og * tanhf(c);
      h1s[tid] = hn;
    }
    __syncthreads();
  }
  if (tid < 10) {
    const float* fr = fc1 + tid * H_;
    float s = 0.f;
#pragma unroll 4
    for (int k = 0; k < H_; ++k) s += h1s[k] * fr[k];
    tmp10[tid] = leakyf(s);
  }
  __syncthreads();
  if (tid < 2) {
    const float* fr = fc2 + tid * 10;
    float s = 0.f;
#pragma unroll
    for (int j = 0; j < 10; ++j) s += tmp10[j] * fr[j];
    out[b * 2 + tid] = leakyf(s);
  }
}

extern "C" void kernel_launch(void* const* d_in, const int* in_sizes, int n_in,
                              void* d_out, int out_size, void* d_ws, size_t ws_size,
                              hipStream_t stream) {
  const float* X = (const float*)d_in[0];
  const int* lengths = (const int*)d_in[1];
  const float* w1 = (const float*)d_in[2];
  const float* w2 = (const float*)d_in[3];
  const float* w3 = (const float*)d_in[4];
  const float* linw = (const float*)d_in[5];
  const float* wih0 = (const float*)d_in[6];
  const float* whh0 = (const float*)d_in[7];
  const float* wih1 = (const float*)d_in[8];
  const float* whh1 = (const float*)d_in[9];
  const float* fc1 = (const float*)d_in[10];
  const float* fc2 = (const float*)d_in[11];

  float* wsf = (float*)d_ws;
  float* conv2o = wsf;                 // 2048*32*165 = 10,813,440 floats
  float* xg0 = wsf + 10813440;         // 2048*512
  float* whh0T = wsf;                  // aliases dead conv2o region
  float* wih1T = wsf + 65536;
  float* whh1T = wsf + 131072;
  float* hs1 = wsf + 196608;
  float* xg1 = wsf + 458752;

  k_conv12<<<2048, 256, 0, stream>>>(X, w1, w2, conv2o);
  k_conv3fe<<<2048, 256, 0, stream>>>(conv2o, w3, linw, wih0, xg0);
  k_tr_all<<<48, 256, 0, stream>>>(whh0, wih1, whh1, whh0T, wih1T, whh1T);
  k_lstm0<<<32, 512, 0, stream>>>(xg0, whh0T, lengths, hs1);
  k_xg1<<<256, 512, 0, stream>>>(hs1, wih1T, xg1);
  k_lstm1<<<32, 512, 0, stream>>>(xg1, whh1T, fc1, fc2, lengths, (float*)d_out);
}

// Round 6
// 376.064 us; speedup vs baseline: 7.5337x; 1.4157x over previous
//
#include <hip/hip_runtime.h>
#include <hip/hip_bf16.h>

#define B_ 32
#define T_ 64
#define H_ 128
#define L2OUT 165
#define L3OUT 54
#define FLAT_ 1728

typedef __attribute__((ext_vector_type(8))) short bf16x8;
typedef __attribute__((ext_vector_type(4))) float f32x4;

__device__ __forceinline__ float leakyf(float v) { return v > 0.f ? v : 0.01f * v; }
__device__ __forceinline__ float sigmoidf_(float v) { return 1.f / (1.f + expf(-v)); }
__device__ __forceinline__ unsigned int bf16rne(float v) {
  unsigned int b = __float_as_uint(v);
  return (b + 0x7FFFu + ((b >> 16) & 1u)) >> 16;
}
__device__ __forceinline__ bf16x8 ldb8(const unsigned short* p) {
  return *(const bf16x8*)p;
}

// ---------------------------------------------------------------------------
// Kernel 0: weight prep. Pre-split (hi/lo bf16) + pre-permute all matmul
// weights once. 1031 blocks x 256 = 263,936 threads, one element each.
//  w2hT[cc][c2][tap*32+c1l], w3hT[c3][tap*32+c2], linw-hl[100][1728],
//  wih0-hl[512][128] (k>=100 zero-padded).
// ---------------------------------------------------------------------------
__global__ __launch_bounds__(256) void k_prep(
    const float* __restrict__ w2, const float* __restrict__ w3,
    const float* __restrict__ linw, const float* __restrict__ wih0,
    unsigned short* __restrict__ w2h, unsigned short* __restrict__ w2l,
    unsigned short* __restrict__ w3h, unsigned short* __restrict__ w3l,
    unsigned short* __restrict__ linwh, unsigned short* __restrict__ linwl,
    unsigned short* __restrict__ wih0h, unsigned short* __restrict__ wih0l) {
  const int e = blockIdx.x * 256 + threadIdx.x;
  float v;
  unsigned short* dh;
  unsigned short* dl;
  int di;
  if (e < 20480) {
    int cc = e / 5120, rem = e - cc * 5120;
    int c2 = rem / 160, r = rem - c2 * 160;
    int tap = r >> 5, c1l = r & 31;
    v = w2[c2 * 640 + (cc * 32 + c1l) * 5 + tap];
    dh = w2h; dl = w2l; di = e;
  } else if (e < 25600) {
    int e2 = e - 20480;
    int c3 = e2 / 160, r = e2 - c3 * 160;
    int tap = r >> 5, c2 = r & 31;
    v = w3[c3 * 160 + c2 * 5 + tap];
    dh = w3h; dl = w3l; di = e2;
  } else if (e < 198400) {
    int e3 = e - 25600;
    v = linw[e3];
    dh = linwh; dl = linwl; di = e3;
  } else {
    int e4 = e - 198400;
    int g = e4 >> 7, k = e4 & 127;
    v = (k < 100) ? wih0[g * 100 + k] : 0.f;
    dh = wih0h; dl = wih0l; di = e4;
  }
  unsigned int hb = bf16rne(v);
  float hf = __uint_as_float(hb << 16);
  unsigned int lb = bf16rne(v - hf);
  dh[di] = (unsigned short)hb;
  dl[di] = (unsigned short)lb;
}

// ---------------------------------------------------------------------------
// Kernel 1: fused conv1 (fp32) + conv2 (MFMA) + conv3 (MFMA). One block/n.
// Ah rows padded to 20 u32 (80 B): frag word-stride 60 == 28 mod 32 ->
// 2 lanes/bank (free). Weight frags read directly from pre-split global
// (L2-resident, 16B-aligned). After conv2, acc -> A3 (bf16, transposed,
// aliases Ah) -> conv3 MFMA -> s3g bf16 [n][c3*54+l3].
// LDS = 6016 + 42560 = 48,576 B -> 3 blocks/CU.
// ---------------------------------------------------------------------------
__global__ __launch_bounds__(256) void k_conv123(
    const float* __restrict__ X, const float* __restrict__ w1,
    const unsigned short* __restrict__ w2h, const unsigned short* __restrict__ w2l,
    const unsigned short* __restrict__ w3h, const unsigned short* __restrict__ w3l,
    unsigned short* __restrict__ s3g) {
  __shared__ __align__(16) float Xs[1504];
  __shared__ __align__(16) unsigned int AhU[532 * 20];  // rows 20 u32 (16 data + 4 pad)

  const int n = blockIdx.x;
  const int tid = threadIdx.x;
  const int lane = tid & 63;
  const int w = tid >> 6;
  const int l15 = lane & 15;
  const int cg = lane >> 4;
  const int pr = tid & 15;
  const int po = tid >> 4;

  const float* Xn = X + (size_t)n * 1500;
  for (int i = tid; i < 1500; i += 256) Xs[i] = Xn[i];
  if (tid < 4) Xs[1500 + tid] = 0.f;
  for (int i = tid; i < 640; i += 256) AhU[10000 + i] = 0u;  // rows 500..531

  f32x4 acc[3][2];
#pragma unroll
  for (int a = 0; a < 3; ++a)
#pragma unroll
    for (int m = 0; m < 2; ++m) acc[a][m] = (f32x4){0.f, 0.f, 0.f, 0.f};

  for (int cc = 0; cc < 4; ++cc) {  // 4 chunks of 32 c1
    __syncthreads();
    // conv1: thread covers c1 pair (2pr, 2pr+1), positions po+16i
    const float* wA = w1 + (cc * 32 + 2 * pr) * 5;
    float a0 = wA[0], a1 = wA[1], a2 = wA[2], a3 = wA[3], a4 = wA[4];
    float b0 = wA[5], b1 = wA[6], b2 = wA[7], b3 = wA[8], b4 = wA[9];
#pragma unroll 2
    for (int i = 0; i < 32; ++i) {
      int pos = po + 16 * i;
      if (pos < 500) {
        const float* xp = Xs + 3 * pos;
        float x0 = xp[0], x1 = xp[1], x2 = xp[2], x3 = xp[3], x4 = xp[4];
        float vA = fmaf(x4, a4, fmaf(x3, a3, fmaf(x2, a2, fmaf(x1, a1, x0 * a0))));
        float vB = fmaf(x4, b4, fmaf(x3, b3, fmaf(x2, b2, fmaf(x1, b1, x0 * b0))));
        vA = leakyf(vA);
        vB = leakyf(vB);
        AhU[pos * 20 + pr] = bf16rne(vA) | (bf16rne(vB) << 16);
      }
    }
    __syncthreads();
    // conv2 MFMA: W-frags from global (L2), B-frags from LDS (conflict-free)
    const unsigned short* w2hB = w2h + cc * 5120;
    const unsigned short* w2lB = w2l + cc * 5120;
#pragma unroll
    for (int tap = 0; tap < 5; ++tap) {
      const int wc = tap * 32 + cg * 8;
      bf16x8 ah0 = ldb8(w2hB + l15 * 160 + wc);
      bf16x8 ah1 = ldb8(w2hB + (l15 + 16) * 160 + wc);
      bf16x8 al0 = ldb8(w2lB + l15 * 160 + wc);
      bf16x8 al1 = ldb8(w2lB + (l15 + 16) * 160 + wc);
#pragma unroll
      for (int nti = 0; nti < 3; ++nti) {
        int nt = w + 4 * nti;
        if (nt < 11) {
          bf16x8 bfr = ldb8((const unsigned short*)AhU + (3 * (nt * 16 + l15) + tap) * 40 + cg * 8);
          acc[nti][0] = __builtin_amdgcn_mfma_f32_16x16x32_bf16(ah0, bfr, acc[nti][0], 0, 0, 0);
          acc[nti][0] = __builtin_amdgcn_mfma_f32_16x16x32_bf16(al0, bfr, acc[nti][0], 0, 0, 0);
          acc[nti][1] = __builtin_amdgcn_mfma_f32_16x16x32_bf16(ah1, bfr, acc[nti][1], 0, 0, 0);
          acc[nti][1] = __builtin_amdgcn_mfma_f32_16x16x32_bf16(al1, bfr, acc[nti][1], 0, 0, 0);
        }
      }
    }
  }
  __syncthreads();  // all conv2 MFMA reads of Ah done
  // A3 (aliases AhU): rows = l2 (0..195), 16 u32 of c2-pairs; zero pad rows
  for (int i = tid; i < 400; i += 256) AhU[176 * 20 + i] = 0u;
#pragma unroll
  for (int nti = 0; nti < 3; ++nti) {
    int nt = w + 4 * nti;
    if (nt < 11) {
      int l2 = nt * 16 + l15;
#pragma unroll
      for (int mt = 0; mt < 2; ++mt) {
#pragma unroll
        for (int j = 0; j < 2; ++j) {
          float e0 = leakyf(acc[nti][mt][2 * j]);
          float e1 = leakyf(acc[nti][mt][2 * j + 1]);
          AhU[l2 * 20 + mt * 8 + cg * 2 + j] = bf16rne(e0) | (bf16rne(e1) << 16);
        }
      }
    }
  }
  __syncthreads();
  // conv3 MFMA: wave w = n-tile (l3 = w*16+l15), M=32 c3 (2 m-tiles)
  f32x4 a3[2];
  a3[0] = (f32x4){0.f, 0.f, 0.f, 0.f};
  a3[1] = (f32x4){0.f, 0.f, 0.f, 0.f};
#pragma unroll
  for (int tap = 0; tap < 5; ++tap) {
    const int wc = tap * 32 + cg * 8;
    bf16x8 wh0 = ldb8(w3h + l15 * 160 + wc);
    bf16x8 wh1 = ldb8(w3h + (l15 + 16) * 160 + wc);
    bf16x8 wl0 = ldb8(w3l + l15 * 160 + wc);
    bf16x8 wl1 = ldb8(w3l + (l15 + 16) * 160 + wc);
    bf16x8 bfr = ldb8((const unsigned short*)AhU + (3 * (w * 16 + l15) + tap) * 40 + cg * 8);
    a3[0] = __builtin_amdgcn_mfma_f32_16x16x32_bf16(wh0, bfr, a3[0], 0, 0, 0);
    a3[0] = __builtin_amdgcn_mfma_f32_16x16x32_bf16(wl0, bfr, a3[0], 0, 0, 0);
    a3[1] = __builtin_amdgcn_mfma_f32_16x16x32_bf16(wh1, bfr, a3[1], 0, 0, 0);
    a3[1] = __builtin_amdgcn_mfma_f32_16x16x32_bf16(wl1, bfr, a3[1], 0, 0, 0);
  }
  int l3 = w * 16 + l15;
  if (l3 < L3OUT) {
#pragma unroll
    for (int mt = 0; mt < 2; ++mt) {
#pragma unroll
      for (int r = 0; r < 4; ++r) {
        int c3 = mt * 16 + cg * 4 + r;
        s3g[(size_t)n * FLAT_ + c3 * L3OUT + l3] = (unsigned short)bf16rne(leakyf(a3[mt][r]));
      }
    }
  }
}

// ---------------------------------------------------------------------------
// Kernel 2: GEMM-1  fe[2048][112] = s3g[2048][1728] @ linw-hl^T. 64 blocks
// (M-tile 32), 512 thr (8 waves: mi=w&1, n-tiles {nh, nh+4}, nh=w>>1).
// LDS rows padded to 72 shorts (144 B): stride 36 words == 4 mod 32 -> free.
// Epilogue splits fe hi/lo bf16 (kills fe rounding in GEMM-2).
// ---------------------------------------------------------------------------
__global__ __launch_bounds__(512) void k_gemm_fe(
    const unsigned short* __restrict__ s3g,
    const unsigned short* __restrict__ linwh, const unsigned short* __restrict__ linwl,
    unsigned short* __restrict__ feh, unsigned short* __restrict__ fel) {
  __shared__ __align__(16) unsigned short As[32 * 72];
  __shared__ __align__(16) unsigned short Bh[112 * 72];
  __shared__ __align__(16) unsigned short Bl[112 * 72];

  const int m0 = blockIdx.x * 32;
  const int tid = threadIdx.x;
  const int lane = tid & 63;
  const int w = tid >> 6;
  const int l15 = lane & 15;
  const int cg = lane >> 4;
  const int mi = w & 1;
  const int nh = w >> 1;

  f32x4 acc0 = (f32x4){0.f, 0.f, 0.f, 0.f};
  f32x4 acc1 = (f32x4){0.f, 0.f, 0.f, 0.f};

  for (int kc = 0; kc < 27; ++kc) {
    const int k0 = kc * 64;
    __syncthreads();
    if (tid < 256) {
      int r = tid >> 3, s = tid & 7;
      *(bf16x8*)(As + r * 72 + s * 8) = ldb8(s3g + (size_t)(m0 + r) * FLAT_ + k0 + s * 8);
    }
    for (int i = tid; i < 1792; i += 512) {
      int arr = i / 896, j = i - arr * 896;
      int r = j >> 3, s = j & 7;
      bf16x8 v = (bf16x8){0, 0, 0, 0, 0, 0, 0, 0};
      if (r < 100) v = ldb8((arr ? linwl : linwh) + (size_t)r * FLAT_ + k0 + s * 8);
      *(bf16x8*)((arr ? Bl : Bh) + r * 72 + s * 8) = v;
    }
    __syncthreads();
#pragma unroll
    for (int ks = 0; ks < 2; ++ks) {
      bf16x8 af = ldb8(As + (mi * 16 + l15) * 72 + ks * 32 + cg * 8);
      bf16x8 b0h = ldb8(Bh + (nh * 16 + l15) * 72 + ks * 32 + cg * 8);
      bf16x8 b0l = ldb8(Bl + (nh * 16 + l15) * 72 + ks * 32 + cg * 8);
      acc0 = __builtin_amdgcn_mfma_f32_16x16x32_bf16(af, b0h, acc0, 0, 0, 0);
      acc0 = __builtin_amdgcn_mfma_f32_16x16x32_bf16(af, b0l, acc0, 0, 0, 0);
      if (nh < 3) {
        bf16x8 b1h = ldb8(Bh + ((nh + 4) * 16 + l15) * 72 + ks * 32 + cg * 8);
        bf16x8 b1l = ldb8(Bl + ((nh + 4) * 16 + l15) * 72 + ks * 32 + cg * 8);
        acc1 = __builtin_amdgcn_mfma_f32_16x16x32_bf16(af, b1h, acc1, 0, 0, 0);
        acc1 = __builtin_amdgcn_mfma_f32_16x16x32_bf16(af, b1l, acc1, 0, 0, 0);
      }
    }
  }
  const int sample = m0 + mi * 16 + cg * 4;
#pragma unroll
  for (int t = 0; t < 2; ++t) {
    if (t == 1 && nh >= 3) break;
    int jcol = (nh + 4 * t) * 16 + l15;
    f32x4 av = t ? acc1 : acc0;
#pragma unroll
    for (int r = 0; r < 4; ++r) {
      float v = av[r];
      unsigned int hb = bf16rne(v);
      float hf = __uint_as_float(hb << 16);
      unsigned int lb = bf16rne(v - hf);
      feh[(size_t)(sample + r) * 128 + jcol] = (unsigned short)hb;
      fel[(size_t)(sample + r) * 128 + jcol] = (unsigned short)lb;
    }
  }
}

// ---------------------------------------------------------------------------
// Kernel 3: GEMM-2  xg0[2048][512] = fe-hl[2048][128] @ wih0-hl^T.
// K=128 (4 K-steps), no LDS, all frags from global (L2). Grid (32,4), 256 thr.
// 3-pass hi/lo (AhBh + AhBl + AlBh).
// ---------------------------------------------------------------------------
__global__ __launch_bounds__(256) void k_gemm_xg0(
    const unsigned short* __restrict__ feh, const unsigned short* __restrict__ fel,
    const unsigned short* __restrict__ wih0h, const unsigned short* __restrict__ wih0l,
    float* __restrict__ xg0) {
  const int m0 = blockIdx.x * 64;
  const int n0 = blockIdx.y * 128;
  const int tid = threadIdx.x;
  const int lane = tid & 63;
  const int w = tid >> 6;
  const int l15 = lane & 15;
  const int cg = lane >> 4;

  f32x4 acc[8];
#pragma unroll
  for (int i = 0; i < 8; ++i) acc[i] = (f32x4){0.f, 0.f, 0.f, 0.f};

  const int arow = m0 + w * 16 + l15;
#pragma unroll
  for (int ks = 0; ks < 4; ++ks) {
    bf16x8 ah = ldb8(feh + (size_t)arow * 128 + ks * 32 + cg * 8);
    bf16x8 al = ldb8(fel + (size_t)arow * 128 + ks * 32 + cg * 8);
#pragma unroll
    for (int nt = 0; nt < 8; ++nt) {
      int brow = n0 + nt * 16 + l15;
      bf16x8 bh = ldb8(wih0h + (size_t)brow * 128 + ks * 32 + cg * 8);
      bf16x8 bl = ldb8(wih0l + (size_t)brow * 128 + ks * 32 + cg * 8);
      acc[nt] = __builtin_amdgcn_mfma_f32_16x16x32_bf16(ah, bh, acc[nt], 0, 0, 0);
      acc[nt] = __builtin_amdgcn_mfma_f32_16x16x32_bf16(ah, bl, acc[nt], 0, 0, 0);
      acc[nt] = __builtin_amdgcn_mfma_f32_16x16x32_bf16(al, bh, acc[nt], 0, 0, 0);
    }
  }
#pragma unroll
  for (int nt = 0; nt < 8; ++nt) {
#pragma unroll
    for (int r = 0; r < 4; ++r) {
      xg0[(size_t)(m0 + w * 16 + cg * 4 + r) * 512 + n0 + nt * 16 + l15] = acc[nt][r];
    }
  }
}

// ---------------------------------------------------------------------------
// Kernel 4: tiled transpose of the 3 recurrent weight mats [512x128]->[128x512]
// ---------------------------------------------------------------------------
__global__ __launch_bounds__(256) void k_tr_all(
    const float* __restrict__ s0, const float* __restrict__ s1_,
    const float* __restrict__ s2_, float* __restrict__ d0,
    float* __restrict__ d1, float* __restrict__ d2) {
  __shared__ float tile[64][65];
  const int bid = blockIdx.x;
  const int m = bid >> 4, t = bid & 15;
  const int jt = t >> 1, kt = t & 1;
  const float* src = (m == 0) ? s0 : ((m == 1) ? s1_ : s2_);
  float* dst = (m == 0) ? d0 : ((m == 1) ? d1 : d2);
  const int c = threadIdx.x & 63, r0 = threadIdx.x >> 6;
#pragma unroll
  for (int q = 0; q < 16; ++q) {
    int r = r0 + 4 * q;
    tile[r][c] = src[(jt * 64 + r) * 128 + kt * 64 + c];
  }
  __syncthreads();
#pragma unroll
  for (int q = 0; q < 16; ++q) {
    int r = r0 + 4 * q;
    dst[(kt * 64 + r) * 512 + jt * 64 + c] = tile[c][r];
  }
}

// ---------------------------------------------------------------------------
// Kernel 5: LSTM layer 0. 32 blocks x 512 thr; whh0 row held in 128 VGPRs.
// ---------------------------------------------------------------------------
__global__ __launch_bounds__(512) void k_lstm0(
    const float* __restrict__ xg0, const float* __restrict__ whh0T,
    const int* __restrict__ lengths, float* __restrict__ hs1) {
  __shared__ __align__(16) float h0s[H_];
  __shared__ float gs[512];
  const int b = blockIdx.x;
  const int tid = threadIdx.x;
  float w[128];
#pragma unroll
  for (int k = 0; k < 128; ++k) w[k] = whh0T[k * 512 + tid];
  if (tid < H_) h0s[tid] = 0.f;
  float c = 0.f;
  const int len = lengths[b];
  __syncthreads();
  for (int t = 0; t < len; ++t) {
    float a0 = xg0[((size_t)(b * T_ + t)) * 512 + tid];
    float a1 = 0.f;
#pragma unroll
    for (int k4 = 0; k4 < 32; k4 += 2) {
      float4 h = *(const float4*)(h0s + 4 * k4);
      a0 += h.x * w[4 * k4] + h.y * w[4 * k4 + 1] + h.z * w[4 * k4 + 2] + h.w * w[4 * k4 + 3];
      float4 h2 = *(const float4*)(h0s + 4 * k4 + 4);
      a1 += h2.x * w[4 * k4 + 4] + h2.y * w[4 * k4 + 5] + h2.z * w[4 * k4 + 6] + h2.w * w[4 * k4 + 7];
    }
    gs[tid] = a0 + a1;
    __syncthreads();
    if (tid < H_) {
      float ig = sigmoidf_(gs[tid]);
      float fg = sigmoidf_(gs[H_ + tid]);
      float gg = tanhf(gs[2 * H_ + tid]);
      float og = sigmoidf_(gs[3 * H_ + tid]);
      c = fg * c + ig * gg;
      float hn = og * tanhf(c);
      h0s[tid] = hn;
      hs1[((size_t)(b * T_ + t)) * H_ + tid] = hn;
    }
    __syncthreads();
  }
}

// ---------------------------------------------------------------------------
// Kernel 6: xg1 = hs1 @ wih1^T. 256 blocks x 512 thr, 8 rows per block.
// ---------------------------------------------------------------------------
__global__ __launch_bounds__(512) void k_xg1(
    const float* __restrict__ hs1, const float* __restrict__ wih1T,
    float* __restrict__ xg1) {
  __shared__ __align__(16) float hsS[8][128];
  const int r0 = blockIdx.x * 8;
  const int tid = threadIdx.x;
  for (int i = tid; i < 8 * 128; i += 512) ((float*)hsS)[i] = hs1[(size_t)r0 * 128 + i];
  __syncthreads();
  float acc[8] = {0.f, 0.f, 0.f, 0.f, 0.f, 0.f, 0.f, 0.f};
#pragma unroll 4
  for (int k4 = 0; k4 < 32; ++k4) {
    float w0 = wih1T[(4 * k4 + 0) * 512 + tid];
    float w1v = wih1T[(4 * k4 + 1) * 512 + tid];
    float w2v = wih1T[(4 * k4 + 2) * 512 + tid];
    float w3v = wih1T[(4 * k4 + 3) * 512 + tid];
#pragma unroll
    for (int i = 0; i < 8; ++i) {
      float4 h = *(const float4*)(&hsS[i][4 * k4]);
      acc[i] += h.x * w0 + h.y * w1v + h.z * w2v + h.w * w3v;
    }
  }
#pragma unroll
  for (int i = 0; i < 8; ++i) xg1[((size_t)(r0 + i)) * 512 + tid] = acc[i];
}

// ---------------------------------------------------------------------------
// Kernel 7: LSTM layer 1 + FC tail. 32 blocks x 512 thr.
// ---------------------------------------------------------------------------
__global__ __launch_bounds__(512) void k_lstm1(
    const float* __restrict__ xg1, const float* __restrict__ whh1T,
    const float* __restrict__ fc1, const float* __restrict__ fc2,
    const int* __restrict__ lengths, float* __restrict__ out) {
  __shared__ __align__(16) float h1s[H_];
  __shared__ float gs[512];
  __shared__ float tmp10[10];
  const int b = blockIdx.x;
  const int tid = threadIdx.x;
  float w[128];
#pragma unroll
  for (int k = 0; k < 128; ++k) w[k] = whh1T[k * 512 + tid];
  if (tid < H_) h1s[tid] = 0.f;
  float c = 0.f;
  const int len = lengths[b];
  __syncthreads();
  for (int t = 0; t < len; ++t) {
    float a0 = xg1[((size_t)(b * T_ + t)) * 512 + tid];
    float a1 = 0.f;
#pragma unroll
    for (int k4 = 0; k4 < 32; k4 += 2) {
      float4 h = *(const float4*)(h1s + 4 * k4);
      a0 += h.x * w[4 * k4] + h.y * w[4 * k4 + 1] + h.z * w[4 * k4 + 2] + h.w * w[4 * k4 + 3];
      float4 h2 = *(const float4*)(h1s + 4 * k4 + 4);
      a1 += h2.x * w[4 * k4 + 4] + h2.y * w[4 * k4 + 5] + h2.z * w[4 * k4 + 6] + h2.w * w[4 * k4 + 7];
    }
    gs[tid] = a0 + a1;
    __syncthreads();
    if (tid < H_) {
      float ig = sigmoidf_(gs[tid]);
      float fg = sigmoidf_(gs[H_ + tid]);
      float gg = tanhf(gs[2 * H_ + tid]);
      float og = sigmoidf_(gs[3 * H_ + tid]);
      c = fg * c + ig * gg;
      float hn = og * tanhf(c);
      h1s[tid] = hn;
    }
    __syncthreads();
  }
  if (tid < 10) {
    const float* fr = fc1 + tid * H_;
    float s = 0.f;
#pragma unroll 4
    for (int k = 0; k < H_; ++k) s += h1s[k] * fr[k];
    tmp10[tid] = leakyf(s);
  }
  __syncthreads();
  if (tid < 2) {
    const float* fr = fc2 + tid * 10;
    float s = 0.f;
#pragma unroll
    for (int j = 0; j < 10; ++j) s += tmp10[j] * fr[j];
    out[b * 2 + tid] = leakyf(s);
  }
}

extern "C" void kernel_launch(void* const* d_in, const int* in_sizes, int n_in,
                              void* d_out, int out_size, void* d_ws, size_t ws_size,
                              hipStream_t stream) {
  const float* X = (const float*)d_in[0];
  const int* lengths = (const int*)d_in[1];
  const float* w1 = (const float*)d_in[2];
  const float* w2 = (const float*)d_in[3];
  const float* w3 = (const float*)d_in[4];
  const float* linw = (const float*)d_in[5];
  const float* wih0 = (const float*)d_in[6];
  const float* whh0 = (const float*)d_in[7];
  const float* wih1 = (const float*)d_in[8];
  const float* whh1 = (const float*)d_in[9];
  const float* fc1 = (const float*)d_in[10];
  const float* fc2 = (const float*)d_in[11];

  char* wsb = (char*)d_ws;
  size_t off = 0;
  auto alloc = [&](size_t bytes) {
    char* p = wsb + off;
    off += (bytes + 511) & ~(size_t)511;
    return p;
  };
  unsigned short* s3g = (unsigned short*)alloc(2048 * 1728 * 2);      // bf16
  unsigned short* feh = (unsigned short*)alloc(2048 * 128 * 2);
  unsigned short* fel = (unsigned short*)alloc(2048 * 128 * 2);
  float* xg0 = (float*)alloc(2048 * 512 * 4);
  unsigned short* w2h = (unsigned short*)alloc(20480 * 2);
  unsigned short* w2l = (unsigned short*)alloc(20480 * 2);
  unsigned short* w3h = (unsigned short*)alloc(5120 * 2);
  unsigned short* w3l = (unsigned short*)alloc(5120 * 2);
  unsigned short* linwh = (unsigned short*)alloc(172800 * 2);
  unsigned short* linwl = (unsigned short*)alloc(172800 * 2);
  unsigned short* wih0h = (unsigned short*)alloc(65536 * 2);
  unsigned short* wih0l = (unsigned short*)alloc(65536 * 2);
  float* whh0T = (float*)alloc(65536 * 4);
  float* wih1T = (float*)alloc(65536 * 4);
  float* whh1T = (float*)alloc(65536 * 4);
  float* hs1 = (float*)alloc(262144 * 4);
  float* xg1 = (float*)alloc(2048 * 512 * 4);

  k_prep<<<1031, 256, 0, stream>>>(w2, w3, linw, wih0, w2h, w2l, w3h, w3l,
                                   linwh, linwl, wih0h, wih0l);
  k_tr_all<<<48, 256, 0, stream>>>(whh0, wih1, whh1, whh0T, wih1T, whh1T);
  k_conv123<<<2048, 256, 0, stream>>>(X, w1, w2h, w2l, w3h, w3l, s3g);
  k_gemm_fe<<<64, 512, 0, stream>>>(s3g, linwh, linwl, feh, fel);
  k_gemm_xg0<<<dim3(32, 4), 256, 0, stream>>>(feh, fel, wih0h, wih0l, xg0);
  k_lstm0<<<32, 512, 0, stream>>>(xg0, whh0T, lengths, hs1);
  k_xg1<<<256, 512, 0, stream>>>(hs1, wih1T, xg1);
  k_lstm1<<<32, 512, 0, stream>>>(xg1, whh1T, fc1, fc2, lengths, (float*)d_out);
}